// Round 12
// baseline (629.747 us; speedup 1.0000x reference)
//
#include <hip/hip_runtime.h>
#include <hip/hip_bf16.h>
#include <math.h>

// Problem constants
constexpr int N_   = 4096;
constexpr int E_   = 131072;
constexpr int D_   = 256;
constexpr int DIN_ = 16;
constexpr int D3_  = 768;   // 3*D
constexpr int HD_  = 128;   // head dim

typedef __bf16 bf16_8 __attribute__((ext_vector_type(8)));
typedef float  f32x4  __attribute__((ext_vector_type(4)));
typedef float  f32x4v __attribute__((ext_vector_type(4)));
typedef unsigned int u32x4 __attribute__((ext_vector_type(4)));   // NT-store-compatible 16B

// ---- bf16 helpers ----
__device__ __forceinline__ unsigned short f2b(float f) {
  unsigned int u = __float_as_uint(f);
  u = u + 0x7fffu + ((u >> 16) & 1u);   // round-to-nearest-even
  return (unsigned short)(u >> 16);
}
__device__ __forceinline__ float b2f(unsigned short s) {
  return __uint_as_float(((unsigned int)s) << 16);
}
__device__ __forceinline__ unsigned int pack2(unsigned short lo, unsigned short hi) {
  return (unsigned int)lo | ((unsigned int)hi << 16);
}
__device__ __forceinline__ bf16_8 frag16(const unsigned short* p) {
  uint4 v = *(const uint4*)p;           // 16B load (LDS b128 or global dwordx4)
  return __builtin_bit_cast(bf16_8, v);
}
__device__ __forceinline__ float4 ntload4(const void* p) {
  f32x4v v = __builtin_nontemporal_load((const f32x4v*)p);
  float4 r;
  r.x = v[0]; r.y = v[1]; r.z = v[2]; r.w = v[3];
  return r;
}
__device__ __forceinline__ void ntstore16(void* dst, uint4 v) {
  __builtin_nontemporal_store(__builtin_bit_cast(u32x4, v), (u32x4*)dst);
}
// async global->LDS, 16B per lane; LDS dst = uniform base + lane*16
__device__ __forceinline__ void gl2lds16(const unsigned short* g, unsigned short* l) {
  __builtin_amdgcn_global_load_lds(
      (const __attribute__((address_space(1))) void*)g,
      (__attribute__((address_space(3))) void*)l, 16, 0, 0);
}

// Python scalar may arrive as int32 or float32 bits; values here are small ints.
__device__ __forceinline__ float scalar_as_float(const void* p) {
  int iv = *(const int*)p;
  if (iv >= 1 && iv <= 1000000) return (float)iv;  // plausible int
  return __int_as_float(iv);                       // else float bits
}

__device__ __forceinline__ float gelu_exact(float v) {
  return 0.5f * v * (1.0f + erff(v * 0.70710678118654752f));
}
// tanh-form GELU via hardware exp: ~9 VALU ops vs ~30 for erff.
__device__ __forceinline__ float gelu_fast(float v) {
  float u = 0.7978845608028654f * v * (1.0f + 0.044715f * v * v);
  return v / (1.0f + __expf(-2.0f * u));   // v * sigmoid(2u) == 0.5v(1+tanh(u))
}

// ---------------- f32 -> bf16 convert ----------------
__global__ void k_f2b(const float* __restrict__ src, unsigned short* __restrict__ dst, int n) {
  int i = blockIdx.x * 256 + threadIdx.x;
  if (i < n) dst[i] = f2b(src[i]);
}

// ---------------- merged weight converts (6 tensors, one launch) ----------------
__global__ void k_prep_w(const float* __restrict__ w1, const float* __restrict__ w2,
                         const float* __restrict__ w3, const float* __restrict__ lin_w,
                         const float* __restrict__ ipw, const float* __restrict__ opw,
                         unsigned short* __restrict__ wb1, unsigned short* __restrict__ wb2,
                         unsigned short* __restrict__ wb3, unsigned short* __restrict__ lwb,
                         unsigned short* __restrict__ wqb, unsigned short* __restrict__ opwb) {
  int i = blockIdx.x * 256 + threadIdx.x;
  if (i < 393216) { wb1[i] = f2b(w1[i]); return; }
  i -= 393216;
  if (i < 131072) { wb2[i] = f2b(w2[i]); return; }
  i -= 131072;
  if (i < 4096) { wb3[i] = f2b(w3[i]); return; }
  i -= 4096;
  if (i < 4096) { lwb[i] = f2b(lin_w[i]); return; }
  i -= 4096;
  if (i < 196608) { wqb[i] = f2b(ipw[i]); return; }
  i -= 196608;
  if (i < 65536) { opwb[i] = f2b(opw[i]); }
}

// ---------------- M = W1b @ lin_w  [512][16] bf16;  cb = b1 + W1b @ lin_b  f32 ----
__global__ __launch_bounds__(256) void k_prep_m(
    const float* __restrict__ w1, const float* __restrict__ lin_w,
    const float* __restrict__ lin_b, const float* __restrict__ b1,
    unsigned short* __restrict__ Mb, float* __restrict__ cbv) {
  int idx = blockIdx.x * 256 + threadIdx.x;   // 8192 threads
  int j = idx >> 4, i = idx & 15;
  const float* wr = w1 + (size_t)j * 768 + 256;
  float acc = 0.f;
  for (int kk = 0; kk < 256; ++kk) acc += wr[kk] * lin_w[kk * 16 + i];
  Mb[j * 16 + i] = f2b(acc);
  if (i == 0) {
    float c = b1[j];
    for (int kk = 0; kk < 256; ++kk) c += wr[kk] * lin_b[kk];
    cbv[j] = c;
  }
}

// ---------------- merged Wl/Wg transpose+convert ----------------
__global__ void k_prep_t(const float* __restrict__ Wl, const float* __restrict__ Wg,
                         unsigned short* __restrict__ wlT, unsigned short* __restrict__ wgT) {
  int i = blockIdx.x * 256 + threadIdx.x;          // 2 x 131072
  int seg = i >> 17;
  int idx = i & 131071;
  int k = idx & 511, j = idx >> 9;                 // dst [256][512] <- src [512][256]
  const float* src = seg ? Wg : Wl;
  unsigned short* dst = seg ? wgT : wlT;
  dst[idx] = f2b(src[(size_t)k * 256 + j]);
}

// ---------------- merged input/h0 converts ----------------
__global__ void k_prep_x(const float* __restrict__ input, const float* __restrict__ h0,
                         unsigned short* __restrict__ inb, unsigned short* __restrict__ h0b) {
  int i = blockIdx.x * 256 + threadIdx.x;          // 2 x 2^20
  int seg = i >> 20;
  int idx = i & 1048575;
  if (seg) h0b[idx] = f2b(h0[idx]);
  else     inb[idx] = f2b(input[idx]);
}

// ---------------- copy (float4) ----------------
__global__ void k_copy4(const float4* __restrict__ src, float4* __restrict__ dst, int n4) {
  int idx = blockIdx.x * 256 + threadIdx.x;
  if (idx < n4) dst[idx] = src[idx];
}

// ================= CSR build (per-launch) + gather aggregation =================
__global__ void k_zero(int* __restrict__ p, int n) {
  int i = blockIdx.x * 256 + threadIdx.x;
  if (i < n) p[i] = 0;
}
__global__ void k_hist(const int* __restrict__ adj, int* __restrict__ cnt) {
  int e = blockIdx.x * 256 + threadIdx.x;
  atomicAdd(&cnt[adj[E_ + e]], 1);
}
__global__ __launch_bounds__(1024) void k_scan(const int* __restrict__ cnt,
                                               int* __restrict__ off, int* __restrict__ cur) {
  __shared__ int ps[1024];
  int tid = threadIdx.x;
  int base = tid * 4;
  int a0 = cnt[base], a1 = cnt[base + 1], a2 = cnt[base + 2], a3 = cnt[base + 3];
  int tsum = a0 + a1 + a2 + a3;
  ps[tid] = tsum;
  __syncthreads();
  for (int st = 1; st < 1024; st <<= 1) {
    int v = (tid >= st) ? ps[tid - st] : 0;
    __syncthreads();
    ps[tid] += v;
    __syncthreads();
  }
  int excl = ps[tid] - tsum;
  int o0 = excl, o1 = excl + a0, o2 = o1 + a1, o3 = o2 + a2;
  off[base] = o0; off[base + 1] = o1; off[base + 2] = o2; off[base + 3] = o3;
  cur[base] = o0; cur[base + 1] = o1; cur[base + 2] = o2; cur[base + 3] = o3;
  if (tid == 1023) off[4096] = o3 + a3;
}
__global__ void k_bucket(const int* __restrict__ adj, int* __restrict__ cur,
                         int* __restrict__ perm) {
  int e = blockIdx.x * 256 + threadIdx.x;
  int p = atomicAdd(&cur[adj[E_ + e]], 1);
  perm[p] = e;
}
// Gather with the lin fold: xout[n] = x[n] + sum_e w*x[src]
//   + (sum_e w*dmap[e]) @ lin_w^T + (sum_e w)*lin_b     -- eab never read.
__global__ __launch_bounds__(256) void k_gather(
    const float* __restrict__ x, const int* __restrict__ adj,
    const float* __restrict__ dmap, const float* __restrict__ nrm,
    const float* __restrict__ lin_w, const float* __restrict__ lin_b,
    const int* __restrict__ off, const int* __restrict__ perm,
    float* __restrict__ xout) {
  __shared__ float sds[17];
  int n = blockIdx.x, t = threadIdx.x;
  int beg = off[n], end = off[n + 1];
  float acc = x[(size_t)n * D_ + t];
  float ds = 0.f, ws = 0.f;
  int i = beg;
  for (; i + 1 < end; i += 2) {
    int e0 = perm[i], e1 = perm[i + 1];
    int s0 = adj[e0], s1 = adj[e1];
    float w0 = nrm[e0], w1 = nrm[e1];
    acc += w0 * x[(size_t)s0 * D_ + t] + w1 * x[(size_t)s1 * D_ + t];
    if (t < DIN_) {
      ds += w0 * dmap[(size_t)e0 * DIN_ + t] + w1 * dmap[(size_t)e1 * DIN_ + t];
      ws += w0 + w1;
    }
  }
  if (i < end) {
    int e0 = perm[i];
    int s0 = adj[e0];
    float w0 = nrm[e0];
    acc += w0 * x[(size_t)s0 * D_ + t];
    if (t < DIN_) {
      ds += w0 * dmap[(size_t)e0 * DIN_ + t];
      ws += w0;
    }
  }
  if (t < DIN_) { sds[t] = ds; if (t == 0) sds[16] = ws; }
  __syncthreads();
  float ex = sds[16] * lin_b[t];
  const float4* lw = (const float4*)(lin_w + (size_t)t * DIN_);
  float4 l0 = lw[0], l1 = lw[1], l2 = lw[2], l3 = lw[3];
  ex += sds[0] * l0.x + sds[1] * l0.y + sds[2] * l0.z + sds[3] * l0.w;
  ex += sds[4] * l1.x + sds[5] * l1.y + sds[6] * l1.z + sds[7] * l1.w;
  ex += sds[8] * l2.x + sds[9] * l2.y + sds[10] * l2.z + sds[11] * l2.w;
  ex += sds[12] * l3.x + sds[13] * l3.y + sds[14] * l3.z + sds[15] * l3.w;
  xout[(size_t)n * D_ + t] = acc + ex;
}

// ---------------- legacy scatter (fallback path) ----------------
__global__ __launch_bounds__(256) void k_scatter(
    const float* __restrict__ x, const int* __restrict__ adj,
    const float* __restrict__ dmap, const float* __restrict__ nrm,
    const float* __restrict__ lin_w, const float* __restrict__ lin_b,
    float* __restrict__ xout) {
  __shared__ float s_dm[4][DIN_];
  int te = threadIdx.x >> 6;
  int d4 = threadIdx.x & 63;
  int e  = blockIdx.x * 4 + te;
  if (d4 < DIN_) s_dm[te][d4] = dmap[(size_t)e * DIN_ + d4];
  __syncthreads();
  int vs = adj[e];
  int vd = adj[E_ + e];
  float w = nrm[e];
  int d = d4 * 4;
  float4 xs = *(const float4*)(x + (size_t)vs * D_ + d);
  float ea[4];
#pragma unroll
  for (int q = 0; q < 4; q++) {
    const float* lw = lin_w + (size_t)(d + q) * DIN_;
    float acc = lin_b[d + q];
#pragma unroll
    for (int k = 0; k < DIN_; k++) acc += s_dm[te][k] * lw[k];
    ea[q] = acc;
  }
  float* op = xout + (size_t)vd * D_ + d;
  atomicAdd(op + 0, w * (xs.x + ea[0]));
  atomicAdd(op + 1, w * (xs.y + ea[1]));
  atomicAdd(op + 2, w * (xs.z + ea[2]));
  atomicAdd(op + 3, w * (xs.w + ea[3]));
}

// ---------------- C[M,N] = A[M,K] @ B[N,K]^T + bias (fp32, fallback) ----------------
__global__ __launch_bounds__(256) void k_gemm_bt(
    const float* __restrict__ A, const float* __restrict__ B,
    const float* __restrict__ bias, float* __restrict__ C,
    int M, int Nn, int K) {
  __shared__ float sA[16][68];
  __shared__ float sB[16][68];
  int bm = blockIdx.y * 64, bn = blockIdx.x * 64;
  int tid = threadIdx.x;
  int tr = tid >> 4, tc = tid & 15;
  float acc[4][4] = {};
  for (int k0 = 0; k0 < K; k0 += 16) {
    for (int i = tid; i < 1024; i += 256) {
      int r = i >> 4, c = i & 15;
      sA[c][r] = A[(size_t)(bm + r) * K + k0 + c];
      sB[c][r] = B[(size_t)(bn + r) * K + k0 + c];
    }
    __syncthreads();
#pragma unroll
    for (int kk = 0; kk < 16; kk++) {
      float av[4], bv[4];
#pragma unroll
      for (int i = 0; i < 4; i++) av[i] = sA[kk][tr * 4 + i];
#pragma unroll
      for (int j = 0; j < 4; j++) bv[j] = sB[kk][tc * 4 + j];
#pragma unroll
      for (int i = 0; i < 4; i++)
#pragma unroll
        for (int j = 0; j < 4; j++) acc[i][j] += av[i] * bv[j];
    }
    __syncthreads();
  }
#pragma unroll
  for (int i = 0; i < 4; i++) {
    int r = bm + tr * 4 + i;
#pragma unroll
    for (int j = 0; j < 4; j++) {
      int c = bn + tc * 4 + j;
      C[(size_t)r * Nn + c] = acc[i][j] + bias[c];
    }
  }
}

// ---------------- qkv proj via MFMA: bf16 in, fp32 qkv out ----------------
__global__ __launch_bounds__(256) void k_qkv_mfma(
    const unsigned short* __restrict__ inb, const unsigned short* __restrict__ wqb,
    const float* __restrict__ ipb, float* __restrict__ qkv) {
  __shared__ unsigned short sA[128][72];
  __shared__ unsigned short sB[128][72];
  const int b   = blockIdx.x;
  const int j0  = (b % 6) * 128;
  const int m0  = (b / 6) * 128;
  const int tid = threadIdx.x;
  const int lane = tid & 63, wv = tid >> 6;
  const int r16  = lane & 15, quad = lane >> 4;
  const int sr   = tid >> 1, sh = (tid & 1) * 32;

  const unsigned short* ra = inb + (size_t)(m0 + sr) * D_;
  const unsigned short* rb = wqb + (size_t)(j0 + sr) * D_;

  const f32x4 zz = {0.f, 0.f, 0.f, 0.f};
  f32x4 acc[2][8];
#pragma unroll
  for (int m = 0; m < 2; ++m)
#pragma unroll
    for (int n = 0; n < 8; ++n) acc[m][n] = zz;

  for (int ki = 0; ki < 4; ++ki) {
    __syncthreads();
    {
      const uint4* s    = (const uint4*)(ra + ki * 64 + sh);
      const uint4* bsrc = (const uint4*)(rb + ki * 64 + sh);
      uint4* da = (uint4*)&sA[sr][sh];
      uint4* db = (uint4*)&sB[sr][sh];
#pragma unroll
      for (int i = 0; i < 4; ++i) { da[i] = s[i]; db[i] = bsrc[i]; }
    }
    __syncthreads();
#pragma unroll
    for (int kk = 0; kk < 2; ++kk) {
      bf16_8 a0 = frag16(&sA[wv * 32 + r16][kk * 32 + quad * 8]);
      bf16_8 a1 = frag16(&sA[wv * 32 + 16 + r16][kk * 32 + quad * 8]);
#pragma unroll
      for (int n = 0; n < 8; ++n) {
        bf16_8 bf = frag16(&sB[n * 16 + r16][kk * 32 + quad * 8]);
        acc[0][n] = __builtin_amdgcn_mfma_f32_16x16x32_bf16(a0, bf, acc[0][n], 0, 0, 0);
        acc[1][n] = __builtin_amdgcn_mfma_f32_16x16x32_bf16(a1, bf, acc[1][n], 0, 0, 0);
      }
    }
  }
#pragma unroll
  for (int m = 0; m < 2; ++m)
#pragma unroll
    for (int n = 0; n < 8; ++n) {
      int col = j0 + n * 16 + r16;
      float bb = ipb[col];
#pragma unroll
      for (int rg = 0; rg < 4; ++rg) {
        int row = m0 + wv * 32 + m * 16 + quad * 4 + rg;
        qkv[(size_t)row * D3_ + col] = acc[m][n][rg] + bb;
      }
    }
}

// ---------------- node GEMM: Pac = x_out @ [W1a | W1c]^T, bf16 [4096][1024] ----
__global__ __launch_bounds__(256) void k_node_pac(
    const unsigned short* __restrict__ xbp, const unsigned short* __restrict__ wb1,
    unsigned short* __restrict__ Pac) {
  __shared__ unsigned short sA[128][72];
  __shared__ unsigned short sB[128][72];
  const int b    = blockIdx.x;          // 32 m-tiles x 8 j-tiles
  const int j0   = (b & 7) * 128;
  const int m0   = (b >> 3) * 128;
  const int side = j0 >> 9;             // 0: W1a, 1: W1c
  const int jr   = j0 - side * 512;
  const int tid  = threadIdx.x;
  const int lane = tid & 63, wv = tid >> 6;
  const int r16  = lane & 15, quad = lane >> 4;
  const int sr   = tid >> 1, sh = (tid & 1) * 32;

  const unsigned short* ra = xbp + (size_t)(m0 + sr) * D_;
  const unsigned short* rb = wb1 + (size_t)(jr + sr) * 768 + side * 512;

  const f32x4 zz = {0.f, 0.f, 0.f, 0.f};
  f32x4 acc[2][8];
#pragma unroll
  for (int m = 0; m < 2; ++m)
#pragma unroll
    for (int n = 0; n < 8; ++n) acc[m][n] = zz;

  for (int ki = 0; ki < 4; ++ki) {
    __syncthreads();
    {
      const uint4* s    = (const uint4*)(ra + ki * 64 + sh);
      const uint4* bsrc = (const uint4*)(rb + ki * 64 + sh);
      uint4* da = (uint4*)&sA[sr][sh];
      uint4* db = (uint4*)&sB[sr][sh];
#pragma unroll
      for (int i = 0; i < 4; ++i) { da[i] = s[i]; db[i] = bsrc[i]; }
    }
    __syncthreads();
#pragma unroll
    for (int kk = 0; kk < 2; ++kk) {
      bf16_8 a0 = frag16(&sA[wv * 32 + r16][kk * 32 + quad * 8]);
      bf16_8 a1 = frag16(&sA[wv * 32 + 16 + r16][kk * 32 + quad * 8]);
#pragma unroll
      for (int n = 0; n < 8; ++n) {
        bf16_8 bf = frag16(&sB[n * 16 + r16][kk * 32 + quad * 8]);
        acc[0][n] = __builtin_amdgcn_mfma_f32_16x16x32_bf16(a0, bf, acc[0][n], 0, 0, 0);
        acc[1][n] = __builtin_amdgcn_mfma_f32_16x16x32_bf16(a1, bf, acc[1][n], 0, 0, 0);
      }
    }
  }
#pragma unroll
  for (int m = 0; m < 2; ++m)
#pragma unroll
    for (int n = 0; n < 8; ++n) {
      int col = j0 + n * 16 + r16;
#pragma unroll
      for (int rg = 0; rg < 4; ++rg) {
        int row = m0 + wv * 32 + m * 16 + quad * 4 + rg;
        Pac[(size_t)row * 1024 + col] = f2b(acc[m][n][rg]);
      }
    }
}

// ---------------- out_proj via MFMA: hgl = attob @ opwb^T + opb; hgb = bf16 ----
__global__ __launch_bounds__(256) void k_outproj_mfma(
    const unsigned short* __restrict__ attob, const unsigned short* __restrict__ opwb,
    const float* __restrict__ opb, float* __restrict__ hgl,
    unsigned short* __restrict__ hgb) {
  __shared__ unsigned short sA[128][72];
  __shared__ unsigned short sB[128][72];
  const int b   = blockIdx.x;
  const int j0  = (b & 1) * 128;
  const int m0  = (b >> 1) * 128;
  const int tid = threadIdx.x;
  const int lane = tid & 63, wv = tid >> 6;
  const int r16  = lane & 15, quad = lane >> 4;
  const int sr   = tid >> 1, sh = (tid & 1) * 32;

  const unsigned short* ra = attob + (size_t)(m0 + sr) * D_;
  const unsigned short* rb = opwb + (size_t)(j0 + sr) * D_;

  const f32x4 zz = {0.f, 0.f, 0.f, 0.f};
  f32x4 acc[2][8];
#pragma unroll
  for (int m = 0; m < 2; ++m)
#pragma unroll
    for (int n = 0; n < 8; ++n) acc[m][n] = zz;

  for (int ki = 0; ki < 4; ++ki) {
    __syncthreads();
    {
      const uint4* s    = (const uint4*)(ra + ki * 64 + sh);
      const uint4* bsrc = (const uint4*)(rb + ki * 64 + sh);
      uint4* da = (uint4*)&sA[sr][sh];
      uint4* db = (uint4*)&sB[sr][sh];
#pragma unroll
      for (int i = 0; i < 4; ++i) { da[i] = s[i]; db[i] = bsrc[i]; }
    }
    __syncthreads();
#pragma unroll
    for (int kk = 0; kk < 2; ++kk) {
      bf16_8 a0 = frag16(&sA[wv * 32 + r16][kk * 32 + quad * 8]);
      bf16_8 a1 = frag16(&sA[wv * 32 + 16 + r16][kk * 32 + quad * 8]);
#pragma unroll
      for (int n = 0; n < 8; ++n) {
        bf16_8 bf = frag16(&sB[n * 16 + r16][kk * 32 + quad * 8]);
        acc[0][n] = __builtin_amdgcn_mfma_f32_16x16x32_bf16(a0, bf, acc[0][n], 0, 0, 0);
        acc[1][n] = __builtin_amdgcn_mfma_f32_16x16x32_bf16(a1, bf, acc[1][n], 0, 0, 0);
      }
    }
  }
#pragma unroll
  for (int m = 0; m < 2; ++m)
#pragma unroll
    for (int n = 0; n < 8; ++n) {
      int col = j0 + n * 16 + r16;
      float bb = opb[col];
#pragma unroll
      for (int rg = 0; rg < 4; ++rg) {
        int row = m0 + wv * 32 + m * 16 + quad * 4 + rg;
        float v = acc[m][n][rg] + bb;
        size_t idx = (size_t)row * D_ + col;
        hgl[idx] = v;
        hgb[idx] = f2b(v);
      }
    }
}

// ---------------- final combine via MFMA ----------------
__global__ __launch_bounds__(256) void k_final_mfma(
    const unsigned short* __restrict__ xbp, const unsigned short* __restrict__ h0b,
    const unsigned short* __restrict__ hgb,
    const unsigned short* __restrict__ wlT, const unsigned short* __restrict__ wgT,
    const float* __restrict__ hl, const float* __restrict__ hg, const float* __restrict__ h0,
    const float* __restrict__ alpha_p, const void* lamda_p, const void* l_p,
    float* __restrict__ out) {
  __shared__ unsigned short sA[128][72];
  __shared__ unsigned short sB[128][72];
  const int b   = blockIdx.x;
  const int j0  = (b & 1) * 128;
  const int m0  = (b >> 1) * 128;
  const int tid = threadIdx.x;
  const int lane = tid & 63, wv = tid >> 6;
  const int r16  = lane & 15, quad = lane >> 4;
  const int sr   = tid >> 1, sh = (tid & 1) * 32;

  const f32x4 zz = {0.f, 0.f, 0.f, 0.f};
  f32x4 acc[2][8];
#pragma unroll
  for (int m = 0; m < 2; ++m)
#pragma unroll
    for (int n = 0; n < 8; ++n) acc[m][n] = zz;

  const size_t arow = (size_t)(m0 + sr) * D_;
  const size_t brow = (size_t)(j0 + sr) * 512;

  for (int ki = 0; ki < 16; ++ki) {
    __syncthreads();
    {
      const int gc = ki * 64 + sh;
      const unsigned short* ap =
          (gc < 256) ? xbp + arow + gc
        : (gc < 512) ? h0b + arow + (gc - 256)
        : (gc < 768) ? hgb + arow + (gc - 512)
                     : h0b + arow + (gc - 768);
      const unsigned short* bp = (gc < 512) ? wlT + brow + gc : wgT + brow + (gc - 512);
      const uint4* s    = (const uint4*)ap;
      const uint4* bsrc = (const uint4*)bp;
      uint4* da = (uint4*)&sA[sr][sh];
      uint4* db = (uint4*)&sB[sr][sh];
#pragma unroll
      for (int i = 0; i < 4; ++i) { da[i] = s[i]; db[i] = bsrc[i]; }
    }
    __syncthreads();
#pragma unroll
    for (int kk = 0; kk < 2; ++kk) {
      bf16_8 a0 = frag16(&sA[wv * 32 + r16][kk * 32 + quad * 8]);
      bf16_8 a1 = frag16(&sA[wv * 32 + 16 + r16][kk * 32 + quad * 8]);
#pragma unroll
      for (int n = 0; n < 8; ++n) {
        bf16_8 bf = frag16(&sB[n * 16 + r16][kk * 32 + quad * 8]);
        acc[0][n] = __builtin_amdgcn_mfma_f32_16x16x32_bf16(a0, bf, acc[0][n], 0, 0, 0);
        acc[1][n] = __builtin_amdgcn_mfma_f32_16x16x32_bf16(a1, bf, acc[1][n], 0, 0, 0);
      }
    }
  }
  float theta = fminf(1.f, logf(scalar_as_float(lamda_p) / scalar_as_float(l_p) + 1.f));
  float a = alpha_p[0];
  float omt = 1.f - theta;
#pragma unroll
  for (int m = 0; m < 2; ++m)
#pragma unroll
    for (int n = 0; n < 8; ++n) {
      int col = j0 + n * 16 + r16;
#pragma unroll
      for (int rg = 0; rg < 4; ++rg) {
        int row = m0 + wv * 32 + m * 16 + quad * 4 + rg;
        size_t idx = (size_t)row * D_ + col;
        out[idx] = theta * acc[m][n][rg] +
                   omt * ((1.f - a) * (hl[idx] + hg[idx]) + 2.f * a * h0[idx]);
      }
    }
}

// ---------------- qkv split: fp32 [N,768] -> bf16 Qb/Kb [h][n][128] ----------------
__global__ void k_qk2b(const float* __restrict__ qkv,
                       unsigned short* __restrict__ Qb, unsigned short* __restrict__ Kb) {
  int off = (blockIdx.x * 256 + threadIdx.x) * 8;   // over N*512
  int n = off >> 9, c = off & 511;
  const float* src = qkv + (size_t)n * D3_ + c;     // Q cols 0..255, K cols 256..511
  float4 a = *(const float4*)src;
  float4 b = *(const float4*)(src + 4);
  uint4 p = {pack2(f2b(a.x), f2b(a.y)), pack2(f2b(a.z), f2b(a.w)),
             pack2(f2b(b.x), f2b(b.y)), pack2(f2b(b.z), f2b(b.w))};
  int cc = c & 255;
  int hh = cc >> 7, d = cc & 127;
  unsigned short* dst = (c < 256 ? Qb : Kb) + (size_t)hh * N_ * HD_ + (size_t)n * HD_ + d;
  *(uint4*)dst = p;
}

// ---------------- V transpose: fp32 qkv V-cols -> bf16 Vt [h][128][N] ----------------
__global__ __launch_bounds__(256) void k_v2t(const float* __restrict__ qkv,
                                             unsigned short* __restrict__ Vt) {
  __shared__ unsigned short sv[64][136];
  int h = blockIdx.y;
  int n0 = blockIdx.x * 64;
  int tid = threadIdx.x;
#pragma unroll
  for (int it = 0; it < 4; ++it) {
    int off = (tid + it * 256) * 8;
    int r = off >> 7, d = off & 127;
    const float* src = qkv + (size_t)(n0 + r) * D3_ + 2 * D_ + h * HD_ + d;
    float4 a = *(const float4*)src;
    float4 b = *(const float4*)(src + 4);
    uint4 p = {pack2(f2b(a.x), f2b(a.y)), pack2(f2b(a.z), f2b(a.w)),
               pack2(f2b(b.x), f2b(b.y)), pack2(f2b(b.z), f2b(b.w))};
    *(uint4*)&sv[r][d] = p;
  }
  __syncthreads();
#pragma unroll
  for (int it = 0; it < 4; ++it) {
    int off = (tid + it * 256) * 8;
    int d = off >> 6, k = off & 63;
    unsigned short t[8];
#pragma unroll
    for (int j = 0; j < 8; ++j) t[j] = sv[k + j][d];
    uint4 p = {pack2(t[0], t[1]), pack2(t[2], t[3]),
               pack2(t[4], t[5]), pack2(t[6], t[7])};
    *(uint4*)(Vt + (size_t)h * HD_ * N_ + (size_t)d * N_ + n0 + k) = p;
  }
}

// ---------------- MFMA flash attention, H=2, HD=128 (dual fp32+bf16 out) ----------------
// Verified R6 config (99 us). R7 relayout / R8 split-K both failed to improve:
// the cost is per-iteration orchestration, not aggregate latency. Parked.
__global__ __launch_bounds__(256) void k_attn_mfma(
    const unsigned short* __restrict__ Qb, const unsigned short* __restrict__ Kb,
    const unsigned short* __restrict__ Vt, float* __restrict__ o_out,
    unsigned short* __restrict__ ob) {
  __shared__ unsigned short sK[64][136];   // keys x dims (+8 pad)
  __shared__ unsigned short sV[128][72];   // dims x keys (+8 pad)
  __shared__ float          sS[16][68];    // scores
  __shared__ unsigned short sP[16][72];    // probs bf16 (A-frag layout)
  __shared__ float sm[16], sl[16], sa[16];

  const int tid  = threadIdx.x;
  const int h    = blockIdx.y;
  const int q0   = blockIdx.x * 16;
  const int lane = tid & 63;
  const int wv   = tid >> 6;
  const int r16  = lane & 15;
  const int quad = lane >> 4;

  bf16_8 qf[4];
#pragma unroll
  for (int kk = 0; kk < 4; ++kk)
    qf[kk] = frag16(Qb + (size_t)h * N_ * HD_ + (size_t)(q0 + r16) * HD_ + kk * 32 + quad * 8);

  if (tid < 16) { sm[tid] = -1e30f; sl[tid] = 0.f; }

  const f32x4 zz = {0.f, 0.f, 0.f, 0.f};
  f32x4 o0 = zz, o1 = zz;

  const unsigned short* Kh = Kb + (size_t)h * N_ * HD_;
  const unsigned short* Vh = Vt + (size_t)h * HD_ * N_;

  for (int c0 = 0; c0 < N_; c0 += 64) {
    __syncthreads();
#pragma unroll
    for (int it = 0; it < 4; ++it) {
      int off = (tid + it * 256) * 8;
      int key = off >> 7, d = off & 127;
      *(uint4*)&sK[key][d] = *(const uint4*)(Kh + (size_t)(c0 + key) * HD_ + d);
    }
#pragma unroll
    for (int it = 0; it < 4; ++it) {
      int off = (tid + it * 256) * 8;
      int d = off >> 6, k = off & 63;
      *(uint4*)&sV[d][k] = *(const uint4*)(Vh + (size_t)d * N_ + c0 + k);
    }
    __syncthreads();
    f32x4 s = zz;
#pragma unroll
    for (int kk = 0; kk < 4; ++kk) {
      bf16_8 bf = frag16(&sK[wv * 16 + r16][kk * 32 + quad * 8]);
      s = __builtin_amdgcn_mfma_f32_16x16x32_bf16(qf[kk], bf, s, 0, 0, 0);
    }
    const float sc = 0.08838834764831845f;   // 1/sqrt(128)
#pragma unroll
    for (int r = 0; r < 4; ++r)
      sS[quad * 4 + r][wv * 16 + r16] = s[r] * sc;
    __syncthreads();
    {
      int row = tid >> 4, i = tid & 15;
      float4 v = *(const float4*)&sS[row][i * 4];
      float mx = fmaxf(fmaxf(v.x, v.y), fmaxf(v.z, v.w));
#pragma unroll
      for (int m = 1; m <= 8; m <<= 1) mx = fmaxf(mx, __shfl_xor(mx, m));
      float mo = sm[row];
      float mn = fmaxf(mo, mx);
      float p0 = __expf(v.x - mn), p1 = __expf(v.y - mn);
      float p2 = __expf(v.z - mn), p3 = __expf(v.w - mn);
      float ps = p0 + p1 + p2 + p3;
#pragma unroll
      for (int m = 1; m <= 8; m <<= 1) ps += __shfl_xor(ps, m);
      uint2 pk = {pack2(f2b(p0), f2b(p1)), pack2(f2b(p2), f2b(p3))};
      *(uint2*)&sP[row][i * 4] = pk;
      if (i == 0) {
        float al = __expf(mo - mn);
        sl[row] = sl[row] * al + ps;
        sm[row] = mn;
        sa[row] = al;
      }
    }
    __syncthreads();
    {
      float al0 = sa[quad * 4 + 0], al1 = sa[quad * 4 + 1];
      float al2 = sa[quad * 4 + 2], al3 = sa[quad * 4 + 3];
      o0[0] *= al0; o0[1] *= al1; o0[2] *= al2; o0[3] *= al3;
      o1[0] *= al0; o1[1] *= al1; o1[2] *= al2; o1[3] *= al3;
#pragma unroll
      for (int kk = 0; kk < 2; ++kk) {
        bf16_8 pa = frag16(&sP[r16][kk * 32 + quad * 8]);
        bf16_8 v0 = frag16(&sV[wv * 32 + r16][kk * 32 + quad * 8]);
        bf16_8 v1 = frag16(&sV[wv * 32 + 16 + r16][kk * 32 + quad * 8]);
        o0 = __builtin_amdgcn_mfma_f32_16x16x32_bf16(pa, v0, o0, 0, 0, 0);
        o1 = __builtin_amdgcn_mfma_f32_16x16x32_bf16(pa, v1, o1, 0, 0, 0);
      }
    }
  }
  {
    float i0 = 1.f / sl[quad * 4 + 0], i1 = 1.f / sl[quad * 4 + 1];
    float i2 = 1.f / sl[quad * 4 + 2], i3 = 1.f / sl[quad * 4 + 3];
    float vv[8];
    vv[0] = o0[0] * i0; vv[1] = o0[1] * i1; vv[2] = o0[2] * i2; vv[3] = o0[3] * i3;
    vv[4] = o1[0] * i0; vv[5] = o1[1] * i1; vv[6] = o1[2] * i2; vv[7] = o1[3] * i3;
#pragma unroll
    for (int g = 0; g < 2; ++g)
#pragma unroll
      for (int rg = 0; rg < 4; ++rg) {
        size_t idx = (size_t)(q0 + quad * 4 + rg) * D_ + h * HD_ + wv * 32 + g * 16 + r16;
        float v = vv[g * 4 + rg];
        o_out[idx] = v;
        ob[idx] = f2b(v);
      }
  }
}

// ---------------- final combine (fp32, fallback) ----------------
__global__ __launch_bounds__(256) void k_final(
    const float* __restrict__ hl, const float* __restrict__ hg, const float* __restrict__ h0,
    const float* __restrict__ Wl, const float* __restrict__ Wg,
    const float* __restrict__ alpha_p, const void* lamda_p, const void* l_p,
    float* __restrict__ out) {
  __shared__ float sA[16][68];
  __shared__ float sB[16][68];
  float theta = fminf(1.f, logf(scalar_as_float(lamda_p) / scalar_as_float(l_p) + 1.f));
  float a = alpha_p[0];
  int bm = blockIdx.y * 64, bn = blockIdx.x * 64;
  int tid = threadIdx.x, tr = tid >> 4, tc = tid & 15;
  float acc[4][4] = {};
  for (int k0 = 0; k0 < 1024; k0 += 16) {
    for (int i = tid; i < 1024; i += 256) {
      int r = i >> 4, c = i & 15;
      int k = k0 + c;
      const float* src = (k < 256) ? hl : (k < 512) ? h0 : (k < 768) ? hg : h0;
      sA[c][r] = src[(size_t)(bm + r) * 256 + (k & 255)];
    }
    for (int i = tid; i < 1024; i += 256) {
      int kk = i >> 6, j = i & 63;
      int k = k0 + kk;
      const float* Bp = (k < 512) ? (Wl + (size_t)k * 256) : (Wg + (size_t)(k - 512) * 256);
      sB[kk][j] = Bp[bn + j];
    }
    __syncthreads();
#pragma unroll
    for (int kk = 0; kk < 16; kk++) {
      float av[4], bv[4];
#pragma unroll
      for (int i = 0; i < 4; i++) av[i] = sA[kk][tr * 4 + i];
#pragma unroll
      for (int j = 0; j < 4; j++) bv[j] = sB[kk][tc * 4 + j];
#pragma unroll
      for (int i = 0; i < 4; i++)
#pragma unroll
        for (int j = 0; j < 4; j++) acc[i][j] += av[i] * bv[j];
    }
    __syncthreads();
  }
  float omt = 1.f - theta;
#pragma unroll
  for (int i = 0; i < 4; i++) {
    int r = bm + tr * 4 + i;
#pragma unroll
    for (int j = 0; j < 4; j++) {
      int c = bn + tc * 4 + j;
      size_t idx = (size_t)r * 256 + c;
      out[idx] = theta * acc[i][j] + omt * ((1.f - a) * (hl[idx] + hg[idx]) + 2.f * a * h0[idx]);
    }
  }
}

// ========== fused edge-MLP: t1 build (lin-folded, in-register) + GEMM2 + GEMM3 ==========
// R11: R10's concept with the allocation bug fixed. R10 sized lB at 8192 shorts
// but the wb2 staging writes 32 frag-slots x 512 shorts = 16384 shorts -- the
// gl2lds writes overran into sc and past the allocation (absmax 0.48). Correct
// layout: lB [0,16384) | sc [16384,21248) (4 waves x [16][76]); epilogue reg =
// shm + wv*4224 (16896 <= 21248, reused after the final barrier). A-frags stay
// in registers (afr[2][2] uint4) -- each lane's gelu output IS its own MFMA
// A-operand (verified mapping: R9 slot wv*4+m*2+it at lane*8 == a0/a1 reads).
// LDS 41.5 KB -> 3 blocks/CU (R9: 57.5 KB -> 2). Math identical to passing R9.
__global__ __launch_bounds__(256, 3) void k_mlp_f23(
    const float* __restrict__ dmap, const int* __restrict__ adj,
    const unsigned short* __restrict__ Pac, const unsigned short* __restrict__ Mb,
    const float* __restrict__ cbv,
    const unsigned short* __restrict__ wb2, const float* __restrict__ b2,
    const unsigned short* __restrict__ wb3, const float* __restrict__ b3,
    float* __restrict__ dmo) {
  __shared__ unsigned short shm[21248];   // 41.5 KB: lB [0,16384) | sc [16384,21248)
  unsigned short* lB = shm;               // 32 frag slots x 512 shorts = 16384
  const int e0   = blockIdx.x * 128;
  const int tid  = threadIdx.x;
  const int lane = tid & 63, wv = tid >> 6;
  const int r16  = lane & 15, quad = lane >> 4;

  const int er0 = e0 + wv * 32 + r16;     // m=0 edge for this lane
  const int er1 = er0 + 16;               // m=1 edge
  const int vs0 = adj[er0], vs1 = adj[er1];
  const int vd0 = adj[E_ + er0], vd1 = adj[E_ + er1];
  const unsigned short* pA0 = Pac + (size_t)vs0 * 1024;
  const unsigned short* pA1 = Pac + (size_t)vs1 * 1024;
  const unsigned short* pC0 = Pac + (size_t)vd0 * 1024 + 512;
  const unsigned short* pC1 = Pac + (size_t)vd1 * 1024 + 512;

  const uint4 z4 = make_uint4(0u, 0u, 0u, 0u);
  // dmap A-frags for this wave's two edge tiles (zero-padded K 16->32)
  bf16_8 af[2];
#pragma unroll
  for (int m = 0; m < 2; ++m) {
    uint4 p = z4;
    if (quad < 2) {
      const int edge = m ? er1 : er0;
      const float4* dp = (const float4*)(dmap + (size_t)edge * DIN_ + quad * 8);
      float4 a = dp[0], bq = dp[1];
      p = make_uint4(pack2(f2b(a.x), f2b(a.y)), pack2(f2b(a.z), f2b(a.w)),
                     pack2(f2b(bq.x), f2b(bq.y)), pack2(f2b(bq.z), f2b(bq.w)));
    }
    af[m] = __builtin_bit_cast(bf16_8, p);
  }

  unsigned short* sc = shm + 16384 + wv * 1216;   // per-wave [16][76] mid bounce

  const f32x4 zz = {0.f, 0.f, 0.f, 0.f};
  f32x4 acc[2][16];
#pragma unroll
  for (int m = 0; m < 2; ++m)
#pragma unroll
    for (int n = 0; n < 16; ++n) acc[m][n] = zz;

  for (int ki = 0; ki < 8; ++ki) {
    __syncthreads();   // lB restage safety (prev MFMA reads done)
    // ---- stage wb2 chunk into lB (async; 32 slots total across waves) ----
#pragma unroll
    for (int kk = 0; kk < 2; ++kk)
#pragma unroll
      for (int i = 0; i < 4; ++i) {
        int n = wv * 4 + i;
        gl2lds16(wb2 + (size_t)(n * 16 + r16) * 512 + ki * 64 + kk * 32 + quad * 8,
                 &lB[(n * 2 + kk) * 512]);
      }
    // ---- mid = dmap @ M^T for this chunk's 64 cols ----
    f32x4 am[2][4];
#pragma unroll
    for (int n = 0; n < 4; ++n) {
      uint4 mv = z4;
      if (quad < 2)
        mv = *(const uint4*)(Mb + (size_t)(ki * 64 + n * 16 + r16) * DIN_ + quad * 8);
      bf16_8 bf = __builtin_bit_cast(bf16_8, mv);
      am[0][n] = __builtin_amdgcn_mfma_f32_16x16x32_bf16(af[0], bf, zz, 0, 0, 0);
      am[1][n] = __builtin_amdgcn_mfma_f32_16x16x32_bf16(af[1], bf, zz, 0, 0, 0);
    }
    // ---- per m: bounce mid via sc; add gathered Pa/Pc + cb; gelu -> A-frag regs ----
    uint4 afr[2][2];   // [m][it] -- this lane's GEMM2 A-fragments (no LDS round-trip)
#pragma unroll
    for (int m = 0; m < 2; ++m) {
#pragma unroll
      for (int n = 0; n < 4; ++n)
#pragma unroll
        for (int rg = 0; rg < 4; ++rg)
          sc[(quad * 4 + rg) * 76 + n * 16 + r16] = f2b(am[m][n][rg]);
      // wave-private scratch: in-wave LDS ordering suffices (no barrier)
      const unsigned short* pa = m ? pA1 : pA0;
      const unsigned short* pc = m ? pC1 : pC0;
#pragma unroll
      for (int it = 0; it < 2; ++it) {
        const int c = ki * 64 + it * 32 + quad * 8;
        uint4 midq = *(const uint4*)&sc[r16 * 76 + it * 32 + quad * 8];
        uint4 paq  = *(const uint4*)(pa + c);
        uint4 pcq  = *(const uint4*)(pc + c);
        float4 ba = *(const float4*)(cbv + c);
        float4 bb = *(const float4*)(cbv + c + 4);
        const unsigned int mv[4] = {midq.x, midq.y, midq.z, midq.w};
        const unsigned int pv[4] = {paq.x, paq.y, paq.z, paq.w};
        const unsigned int cv[4] = {pcq.x, pcq.y, pcq.z, pcq.w};
        const float bl[8] = {ba.x, ba.y, ba.z, ba.w, bb.x, bb.y, bb.z, bb.w};
        unsigned short us[8];
#pragma unroll
        for (int j = 0; j < 8; ++j) {
          unsigned short mw = (j & 1) ? (unsigned short)(mv[j >> 1] >> 16)
                                      : (unsigned short)(mv[j >> 1] & 0xffffu);
          unsigned short pw = (j & 1) ? (unsigned short)(pv[j >> 1] >> 16)
                                      : (unsigned short)(pv[j >> 1] & 0xffffu);
          unsigned short cw = (j & 1) ? (unsigned short)(cv[j >> 1] >> 16)
                                      : (unsigned short)(cv[j >> 1] & 0xffffu);
          float v = b2f(mw) + b2f(pw) + b2f(cw) + bl[j];
          us[j] = f2b(gelu_fast(v));
        }
        afr[m][it] = make_uint4(pack2(us[0], us[1]), pack2(us[2], us[3]),
                                pack2(us[4], us[5]), pack2(us[6], us[7]));
      }
    }
    __builtin_amdgcn_s_waitcnt(0);   // drain lB gl2lds before any wave reads
    __syncthreads();
    // ---- GEMM2 MFMA phase (A-frags from registers; lB shared) ----
#pragma unroll
    for (int kk = 0; kk < 2; ++kk) {
      bf16_8 a0 = __builtin_bit_cast(bf16_8, afr[0][kk]);
      bf16_8 a1 = __builtin_bit_cast(bf16_8, afr[1][kk]);
#pragma unroll
      for (int n = 0; n < 16; ++n) {
        bf16_8 bf = frag16(&lB[(n * 2 + kk) * 512 + lane * 8]);
        acc[0][n] = __builtin_amdgcn_mfma_f32_16x16x32_bf16(a0, bf, acc[0][n], 0, 0, 0);
        acc[1][n] = __builtin_amdgcn_mfma_f32_16x16x32_bf16(a1, bf, acc[1][n], 0, 0, 0);
      }
    }
  }
  // ---- epilogue: per-wave padded scratch [16][264]; two m-passes; gemm3 ----
  __syncthreads();   // all compute LDS reads done before shm reuse
  unsigned short* reg = shm + wv * 4224;   // 16*264 = 4224 shorts; 4 waves = 16896 <= 21248
  float bb3 = b3[r16];
#pragma unroll
  for (int m = 0; m < 2; ++m) {
#pragma unroll
    for (int n = 0; n < 16; ++n) {
      float bb = b2[n * 16 + r16];
#pragma unroll
      for (int rg = 0; rg < 4; ++rg)
        reg[(quad * 4 + rg) * 264 + n * 16 + r16] = f2b(gelu_fast(acc[m][n][rg] + bb));
    }
    // wave-private scratch: in-wave LDS ordering suffices (no barrier)
    f32x4 acc3 = zz;
#pragma unroll
    for (int ks = 0; ks < 8; ++ks) {
      bf16_8 a = frag16(&reg[r16 * 264 + ks * 32 + quad * 8]);
      bf16_8 b = frag16(wb3 + (size_t)r16 * 256 + ks * 32 + quad * 8);
      acc3 = __builtin_amdgcn_mfma_f32_16x16x32_bf16(a, b, acc3, 0, 0, 0);
    }
#pragma unroll
    for (int rg = 0; rg < 4; ++rg)
      dmo[(size_t)(e0 + wv * 32 + m * 16 + quad * 4 + rg) * DIN_ + r16] = acc3[rg] + bb3;
  }
}

// ---------------- fused edge MLP (fallback path) ----------------
__global__ __launch_bounds__(256, 3) void k_edge_mlp_mfma(
    const float* __restrict__ xout, const int* __restrict__ adj,
    const float* __restrict__ dmap,
    const float* __restrict__ lin_w, const float* __restrict__ lin_b,
    const unsigned short* __restrict__ wb1, const float* __restrict__ b1,
    const unsigned short* __restrict__ wb2, const float* __restrict__ b2,
    const unsigned short* __restrict__ wb3, const float* __restrict__ b3,
    float* __restrict__ dmo) {
  __shared__ unsigned short sLo[8448];
  __shared__ unsigned short sT1[32][520];
  unsigned short (*sA)[136]  = (unsigned short(*)[136])sLo;
  unsigned short (*sT2)[264] = (unsigned short(*)[264])sLo;

  const int tid  = threadIdx.x;
  const int e0   = blockIdx.x * 32;
  const int lane = tid & 63;
  const int wv   = tid >> 6;
  const int r16  = lane & 15;
  const int quad = lane >> 4;

  const int sr = tid >> 3;
  const int t8 = tid & 7;
  const int se = e0 + sr;
  const int vsrc = adj[se];
  const int vdst = adj[E_ + se];

  float4 pf0, pf1, pf2, pf3;
  float4 dm0, dm1, dm2, dm3;
  {
    const float4* sp = (const float4*)(xout + (size_t)vsrc * D_ + t8 * 16);
    pf0 = sp[0]; pf1 = sp[1]; pf2 = sp[2]; pf3 = sp[3];
  }

  const f32x4 zz = {0.f, 0.f, 0.f, 0.f};
  f32x4 acc1[8][2];
#pragma unroll
  for (int i = 0; i < 8; ++i) { acc1[i][0] = zz; acc1[i][1] = zz; }

  for (int c = 0; c < 6; ++c) {
    const int k0 = c * 128;
    __syncthreads();
    {
      unsigned short tmp[16];
      if (c == 2 || c == 3) {
        int jb = (c - 2) * 128 + t8 * 16;
#pragma unroll
        for (int j = 0; j < 16; ++j) {
          const float4* lw = (const float4*)(lin_w + (size_t)(jb + j) * DIN_);
          float4 w0 = lw[0], w1 = lw[1], w2 = lw[2], w3 = lw[3];
          float acc = lin_b[jb + j];
          acc += dm0.x * w0.x + dm0.y * w0.y + dm0.z * w0.z + dm0.w * w0.w;
          acc += dm1.x * w1.x + dm1.y * w1.y + dm1.z * w1.z + dm1.w * w1.w;
          acc += dm2.x * w2.x + dm2.y * w2.y + dm2.z * w2.z + dm2.w * w2.w;
          acc += dm3.x * w3.x + dm3.y * w3.y + dm3.z * w3.z + dm3.w * w3.w;
          tmp[j] = f2b(acc);
        }
      } else {
        tmp[0]  = f2b(pf0.x); tmp[1]  = f2b(pf0.y); tmp[2]  = f2b(pf0.z); tmp[3]  = f2b(pf0.w);
        tmp[4]  = f2b(pf1.x); tmp[5]  = f2b(pf1.y); tmp[6]  = f2b(pf1.z); tmp[7]  = f2b(pf1.w);
        tmp[8]  = f2b(pf2.x); tmp[9]  = f2b(pf2.y); tmp[10] = f2b(pf2.z); tmp[11] = f2b(pf2.w);
        tmp[12] = f2b(pf3.x); tmp[13] = f2b(pf3.y); tmp[14] = f2b(pf3.z); tmp[15] = f2b(pf3.w);
      }
      unsigned short* dstp = &sA[sr][t8 * 16];
      uint4 q0v = {pack2(tmp[0], tmp[1]),   pack2(tmp[2], tmp[3]),
                   pack2(tmp[4], tmp[5]),   pack2(tmp[6], tmp[7])};
      uint4 q1v = {pack2(tmp[8], tmp[9]),   pack2(tmp[10], tmp[11]),
                   pack2(tmp[12], tmp[13]), pack2(tmp[14], tmp[15])};
      *(uint4*)(dstp) = q0v;
      *(uint4*)(dstp + 8) = q1v;
    }
    if (c == 0) {
      const float4* sp = (const float4*)(xout + (size_t)vsrc * D_ + 128 + t8 * 16);
      pf0 = sp[0]; pf1 = sp[1]; pf2 = sp[2]; pf3 = sp[3];
    } else if (c == 1) {
      const float4* dp = (const float4*)(dmap + (size_t)se * DIN_);
      dm0 = ntload4(dp); dm1 = ntload4(dp + 1); dm2 = ntload4(dp + 2); dm3 = ntload4(dp + 3);
    } else if (c == 3) {
      const float4* sp = (const float4*)(xout + (size_t)vdst * D_ + t8 * 16);
      pf0 = sp[0]; pf1 = sp[1]; pf2 = sp[2]; pf3 = sp[3];
    } else if (c == 4) {
      const float4* sp = (const float4*)(xout + (size_t)vdst * D_ + 128 + t8 * 16);
      pf0 = sp[0]; pf1 = sp[1]; pf2 = sp[2]; pf3 = sp[3];
    }
    __syncthreads();
#pragma unroll
    for (int kk = 0; kk < 4; ++kk) {
      bf16_8 a0 = frag16(&sA[r16][kk * 32 + quad * 8]);
      bf16_8 a1 = frag16(&sA[16 + r16][kk * 32 + quad * 8]);
#pragma unroll
      for (int i = 0; i < 8; ++i) {
        const unsigned short* bp =
            wb1 + (size_t)(wv * 128 + i * 16 + r16) * 768 + k0 + kk * 32 + quad * 8;
        bf16_8 bf = frag16(bp);
        acc1[i][0] = __builtin_amdgcn_mfma_f32_16x16x32_bf16(a0, bf, acc1[i][0], 0, 0, 0);
        acc1[i][1] = __builtin_amdgcn_mfma_f32_16x16x32_bf16(a1, bf, acc1[i][1], 0, 0, 0);
      }
    }
  }
#pragma unroll
  for (int i = 0; i < 8; ++i) {
    int col = wv * 128 + i * 16 + r16;
    float bb = b1[col];
#pragma unroll
    for (int r = 0; r < 4; ++r) {
      int row = quad * 4 + r;
      sT1[row][col] = f2b(gelu_exact(acc1[i][0][r] + bb));
      sT1[row + 16][col] = f2b(gelu_exact(acc1[i][1][r] + bb));
    }
  }
  __syncthreads();

  f32x4 acc2[4][2];
#pragma unroll
  for (int i = 0; i < 4; ++i) { acc2[i][0] = zz; acc2[i][1] = zz; }
#pragma unroll 4
  for (int ks = 0; ks < 16; ++ks) {
    bf16_8 a0 = frag16(&sT1[r16][ks * 32 + quad * 8]);
    bf16_8 a1 = frag16(&sT1[16 + r16][ks * 32 + quad * 8]);
#pragma unroll
    for (int i = 0; i < 4; ++i) {
      const unsigned short* bp =
          wb2 + (size_t)(wv * 64 + i * 16 + r16) * 512 + ks * 32 + quad * 8;
      bf16_8 bf = frag16(bp);
      acc2[i][0] = __builtin_amdgcn_mfma_f32_16x16x32_bf16(a0, bf, acc2[i][0], 0, 0, 0);
      acc2[i][1] = __builtin_amdgcn_mfma_f32_16x16x32_bf16(a1, bf, acc2[i][1], 0, 0, 0);
    }
  }
#pragma unroll
  for (int i = 0; i < 4; ++i) {
    int col = wv * 64 + i * 16 + r16;
    float bb = b2[col];
#pragma unroll
    for (int m = 0; m < 2; ++m)
#pragma unroll
      for (int r = 0; r < 4; ++r) {
        int row = m * 16 + quad * 4 + r;
        sT2[row][col] = f2b(gelu_exact(acc2[i][m][r] + bb));
      }
  }
  __syncthreads();

  if (wv < 2) {
    f32x4 acc3 = zz;
#pragma unroll
    for (int ks = 0; ks < 8; ++ks) {
      bf16_8 a = frag16(&sT2[wv * 16 + r16][ks * 32 + quad * 8]);
      bf16_8 b = frag16(wb3 + (size_t)r16 * 256 + ks * 32 + quad * 8);
      acc3 = __builtin_amdgcn_mfma_f32_16x16x32_bf16(a, b, acc3, 0, 0, 0);
    }
    float bb = b3[r16];
#pragma unroll
    for (int r = 0; r < 4; ++r) {
      int row = wv * 16 + quad * 4 + r;
      __builtin_nontemporal_store(acc3[r] + bb, &dmo[(size_t)(e0 + row) * DIN_ + r16]);
    }
  }
}

extern "C" void kernel_launch(void* const* d_in, const int* in_sizes, int n_in,
                              void* d_out, int out_size, void* d_ws, size_t ws_size,
                              hipStream_t stream) {
  const float* input = (const float*)d_in[0];
  const int*   adj   = (const int*)d_in[1];
  const float* h0    = (const float*)d_in[2];
  const void*  lamda = d_in[3];
  const float* alpha = (const float*)d_in[4];
  const void*  lll   = d_in[5];
  const float* dmap  = (const float*)d_in[6];
  const float* nrm   = (const float*)d_in[7];
  const float* Wl    = (const float*)d_in[8];
  const float* Wg    = (const float*)d_in[9];
  const float* lin_w = (const float*)d_in[10];
  const float* lin_b = (const float*)d_in[11];
  const float* w1    = (const float*)d_in[12];
  const float* b1    = (const float*)d_in[13];
  const float* w2    = (const float*)d_in[14];
  const float* b2    = (const float*)d_in[15];
  const float* w3    = (const float*)d_in[16];
  const float* b3    = (const float*)d_in[17];
  const float* ipw   = (const float*)d_in[18];
  const float* ipb   = (const float*)d_in[19];
  const float* opw   = (const float*)d_in[20];
  const float* opb   = (const float*)d_in[21];
  float* out = (float*)d_out;
  float* dmo = out + (size_t)N_ * D_;

  // ---- workspace layout ----
  float* ws   = (float*)d_ws;
  float* xout = ws;                               // N*D f32
  float* qkv  = xout + (size_t)N_ * D_;           // N*3D f32 (reused late as Pac)
  float* atto = qkv  + (size_t)N_ * 3 * D_;       // N*D f32
  float* hgl  = atto + (size_t)N_ * D_;           // N*D f32
  unsigned short* wb1 = (unsigned short*)(hgl + (size_t)N_ * D_);  // 512*768
  unsigned short* wb2 = wb1 + 512 * 768;          // 256*512
  unsigned short* wb3 = wb2 + 256 * 512;          // 16*256
  unsigned short* Qb  = wb3 + 16 * 256;           // 2*N*128
  unsigned short* Kb  = Qb + 2 * N_ * HD_;        // 2*N*128
  unsigned short* Vt  = Kb + 2 * N_ * HD_;        // 2*128*N
  unsigned short* t1b = Vt + 2 * HD_ * N_;        // retired t1 region (unused fast path)
  unsigned short* t2b = t1b + (size_t)E_ * 512;   // retired eab region (reused below)
  int* cnt  = (int*)(t2b + (size_t)E_ * 256);     // 4096
  int* off  = cnt + 4096;                         // 4097
  int* cur  = off + 4100;                         // 4096
  int* perm = cur + 4096;                         // E
  unsigned short* xbp = (unsigned short*)(perm + E_);  // N*D bf16
  unsigned short* lwb = xbp + (size_t)N_ * D_;    // 256*16 bf16 lin_w (unused fast path)
  unsigned short* inb = lwb + 256 * DIN_;         // N*D bf16 input
  unsigned short* h0b = inb + (size_t)N_ * D_;    // N*D bf16 h0
  unsigned short* hgb = h0b + (size_t)N_ * D_;    // N*D bf16 h_global
  unsigned short* wqb = hgb + (size_t)N_ * D_;    // 768*256 bf16 in_proj
  unsigned short* wlT = wqb + 768 * 256;          // 256*512 bf16 Wl^T
  unsigned short* wgT = wlT + 256 * 512;          // 256*512 bf16 Wg^T
  unsigned short* opwb = wgT + 256 * 512;         // 256*256 bf16 out_proj
  unsigned short* attob = (unsigned short*)qkv;   // N*D bf16 (qkv region reused post-split)
  // Pac overlays the qkv region (12.6 MB >= 8 MB) AFTER out_proj consumed attob.
  unsigned short* Pac = (unsigned short*)qkv;     // 4096*1024 bf16 (8 MB)
  // M-fold scratch lives in the retired eab region (64 MB free).
  unsigned short* Mb_ = t2b;                      // 512*16 bf16
  float* cbv = (float*)(t2b + 8192);              // 512 f32
  const size_t fast_need = (size_t)((char*)(opwb + 256 * 256) - (char*)d_ws);
  const bool fast = ws_size >= fast_need;

  if (fast) {
    // merged preps: weights, Wl/Wg transpose, input/h0 bf16, M/cb fold
    k_prep_w<<<dim3((794624 + 255) / 256), 256, 0, stream>>>(
        w1, w2, w3, lin_w, ipw, opw, wb1, wb2, wb3, lwb, wqb, opwb);
    k_prep_t<<<dim3((262144 + 255) / 256), 256, 0, stream>>>(Wl, Wg, wlT, wgT);
    k_prep_x<<<dim3((2097152 + 255) / 256), 256, 0, stream>>>(input, h0, inb, h0b);
    k_prep_m<<<dim3(32), 256, 0, stream>>>(w1, lin_w, lin_b, b1, Mb_, cbv);

    // CSR build + lin-folded gather aggregation (eab never materialized)
    k_zero<<<dim3(16), 256, 0, stream>>>(cnt, 4096);
    k_hist<<<dim3(E_ / 256), 256, 0, stream>>>(adj, cnt);
    k_scan<<<dim3(1), 1024, 0, stream>>>(cnt, off, cur);
    k_bucket<<<dim3(E_ / 256), 256, 0, stream>>>(adj, cur, perm);
    k_gather<<<dim3(N_), 256, 0, stream>>>(input, adj, dmap, nrm, lin_w, lin_b,
                                           off, perm, xout);
    k_f2b<<<dim3(N_ * D_ / 256), 256, 0, stream>>>(xout, xbp, N_ * D_);

    // MHA: MFMA qkv -> split -> MFMA flash attn (dual out) -> MFMA out_proj
    k_qkv_mfma<<<dim3(192), 256, 0, stream>>>(inb, wqb, ipb, qkv);
    k_qk2b<<<dim3(N_ * 512 / 8 / 256), 256, 0, stream>>>(qkv, Qb, Kb);
    k_v2t<<<dim3(N_ / 64, 2), 256, 0, stream>>>(qkv, Vt);
    k_attn_mfma<<<dim3(N_ / 16, 2), 256, 0, stream>>>(Qb, Kb, Vt, atto, attob);
    k_outproj_mfma<<<dim3(64), 256, 0, stream>>>(attob, opwb, opb, hgl, hgb);

    // output[N,D] via MFMA
    k_final_mfma<<<dim3(64), 256, 0, stream>>>(xbp, h0b, hgb, wlT, wgT,
                                               xout, hgl, h0, alpha, lamda, lll, out);

    // dm_out[E,16]: node GEMM (Pac in retired qkv region) -> fused t1+gemm2+gemm3
    k_node_pac<<<dim3(256), 256, 0, stream>>>(xbp, wb1, Pac);
    k_mlp_f23<<<dim3(E_ / 128), 256, 0, stream>>>(dmap, adj, Pac, Mb_, cbv,
                                                  wb2, b2, wb3, b3, dmo);
  } else {
    k_f2b<<<dim3((512 * 768 + 255) / 256), 256, 0, stream>>>(w1, wb1, 512 * 768);
    k_f2b<<<dim3((256 * 512 + 255) / 256), 256, 0, stream>>>(w2, wb2, 256 * 512);
    k_f2b<<<dim3((16 * 256 + 255) / 256), 256, 0, stream>>>(w3, wb3, 16 * 256);
    k_copy4<<<dim3(N_ * D_ / 4 / 256), 256, 0, stream>>>((const float4*)input, (float4*)xout,
                                                         N_ * D_ / 4);
    k_scatter<<<dim3(E_ / 4), 256, 0, stream>>>(input, adj, dmap, nrm, lin_w, lin_b, xout);
    k_gemm_bt<<<dim3(D3_ / 64, N_ / 64), 256, 0, stream>>>(input, ipw, ipb, qkv, N_, D3_, D_);
    k_qk2b<<<dim3(N_ * 512 / 8 / 256), 256, 0, stream>>>(qkv, Qb, Kb);
    k_v2t<<<dim3(N_ / 64, 2), 256, 0, stream>>>(qkv, Vt);
    k_attn_mfma<<<dim3(N_ / 16, 2), 256, 0, stream>>>(Qb, Kb, Vt, atto, (unsigned short*)qkv);
    k_gemm_bt<<<dim3(D_ / 64, N_ / 64), 256, 0, stream>>>(atto, opw, opb, hgl, N_, D_, D_);
    k_final<<<dim3(4, N_ / 64), 256, 0, stream>>>(xout, hgl, h0, Wl, Wg, alpha, lamda, lll, out);
    k_edge_mlp_mfma<<<dim3(E_ / 32), 256, 0, stream>>>(xout, adj, dmap, lin_w, lin_b,
                                                       wb1, b1, wb2, b2, wb3, b3, dmo);
  }
}

// Round 13
// 527.544 us; speedup vs baseline: 1.1937x; 1.1937x over previous
//
#include <hip/hip_runtime.h>
#include <hip/hip_bf16.h>
#include <math.h>

// Problem constants
constexpr int N_   = 4096;
constexpr int E_   = 131072;
constexpr int D_   = 256;
constexpr int DIN_ = 16;
constexpr int D3_  = 768;   // 3*D
constexpr int HD_  = 128;   // head dim

typedef __bf16 bf16_8 __attribute__((ext_vector_type(8)));
typedef float  f32x4  __attribute__((ext_vector_type(4)));
typedef float  f32x4v __attribute__((ext_vector_type(4)));
typedef unsigned int u32x4 __attribute__((ext_vector_type(4)));   // NT-store-compatible 16B

// ---- bf16 helpers ----
__device__ __forceinline__ unsigned short f2b(float f) {
  unsigned int u = __float_as_uint(f);
  u = u + 0x7fffu + ((u >> 16) & 1u);   // round-to-nearest-even
  return (unsigned short)(u >> 16);
}
__device__ __forceinline__ float b2f(unsigned short s) {
  return __uint_as_float(((unsigned int)s) << 16);
}
__device__ __forceinline__ unsigned int pack2(unsigned short lo, unsigned short hi) {
  return (unsigned int)lo | ((unsigned int)hi << 16);
}
__device__ __forceinline__ bf16_8 frag16(const unsigned short* p) {
  uint4 v = *(const uint4*)p;           // 16B load (LDS b128 or global dwordx4)
  return __builtin_bit_cast(bf16_8, v);
}
__device__ __forceinline__ float4 ntload4(const void* p) {
  f32x4v v = __builtin_nontemporal_load((const f32x4v*)p);
  float4 r;
  r.x = v[0]; r.y = v[1]; r.z = v[2]; r.w = v[3];
  return r;
}
__device__ __forceinline__ void ntstore16(void* dst, uint4 v) {
  __builtin_nontemporal_store(__builtin_bit_cast(u32x4, v), (u32x4*)dst);
}
// async global->LDS, 16B per lane; LDS dst = uniform base + lane*16
__device__ __forceinline__ void gl2lds16(const unsigned short* g, unsigned short* l) {
  __builtin_amdgcn_global_load_lds(
      (const __attribute__((address_space(1))) void*)g,
      (__attribute__((address_space(3))) void*)l, 16, 0, 0);
}

// Python scalar may arrive as int32 or float32 bits; values here are small ints.
__device__ __forceinline__ float scalar_as_float(const void* p) {
  int iv = *(const int*)p;
  if (iv >= 1 && iv <= 1000000) return (float)iv;  // plausible int
  return __int_as_float(iv);                       // else float bits
}

__device__ __forceinline__ float gelu_exact(float v) {
  return 0.5f * v * (1.0f + erff(v * 0.70710678118654752f));
}
// tanh-form GELU via hardware exp: ~9 VALU ops vs ~30 for erff.
__device__ __forceinline__ float gelu_fast(float v) {
  float u = 0.7978845608028654f * v * (1.0f + 0.044715f * v * v);
  return v / (1.0f + __expf(-2.0f * u));   // v * sigmoid(2u) == 0.5v(1+tanh(u))
}

// ---------------- f32 -> bf16 convert ----------------
__global__ void k_f2b(const float* __restrict__ src, unsigned short* __restrict__ dst, int n) {
  int i = blockIdx.x * 256 + threadIdx.x;
  if (i < n) dst[i] = f2b(src[i]);
}

// ---------------- merged weight converts (6 tensors, one launch) ----------------
__global__ void k_prep_w(const float* __restrict__ w1, const float* __restrict__ w2,
                         const float* __restrict__ w3, const float* __restrict__ lin_w,
                         const float* __restrict__ ipw, const float* __restrict__ opw,
                         unsigned short* __restrict__ wb1, unsigned short* __restrict__ wb2,
                         unsigned short* __restrict__ wb3, unsigned short* __restrict__ lwb,
                         unsigned short* __restrict__ wqb, unsigned short* __restrict__ opwb) {
  int i = blockIdx.x * 256 + threadIdx.x;
  if (i < 393216) { wb1[i] = f2b(w1[i]); return; }
  i -= 393216;
  if (i < 131072) { wb2[i] = f2b(w2[i]); return; }
  i -= 131072;
  if (i < 4096) { wb3[i] = f2b(w3[i]); return; }
  i -= 4096;
  if (i < 4096) { lwb[i] = f2b(lin_w[i]); return; }
  i -= 4096;
  if (i < 196608) { wqb[i] = f2b(ipw[i]); return; }
  i -= 196608;
  if (i < 65536) { opwb[i] = f2b(opw[i]); }
}

// ---------------- M = W1b @ lin_w  [512][16] bf16;  cb = b1 + W1b @ lin_b  f32 ----
// W1b = w1 cols 256..511.  Folds the lin layer through W1b so the edge-MLP's
// middle term becomes dmap @ M^T + (cb - b1): K=256 GEMM over eab -> K=16 over
// dmap. Exact algebra; fewer bf16 roundings than the eab path.
__global__ __launch_bounds__(256) void k_prep_m(
    const float* __restrict__ w1, const float* __restrict__ lin_w,
    const float* __restrict__ lin_b, const float* __restrict__ b1,
    unsigned short* __restrict__ Mb, float* __restrict__ cbv) {
  int idx = blockIdx.x * 256 + threadIdx.x;   // 8192 threads
  int j = idx >> 4, i = idx & 15;
  const float* wr = w1 + (size_t)j * 768 + 256;
  float acc = 0.f;
  for (int kk = 0; kk < 256; ++kk) acc += wr[kk] * lin_w[kk * 16 + i];
  Mb[j * 16 + i] = f2b(acc);
  if (i == 0) {
    float c = b1[j];
    for (int kk = 0; kk < 256; ++kk) c += wr[kk] * lin_b[kk];
    cbv[j] = c;
  }
}

// ---------------- merged Wl/Wg transpose+convert ----------------
__global__ void k_prep_t(const float* __restrict__ Wl, const float* __restrict__ Wg,
                         unsigned short* __restrict__ wlT, unsigned short* __restrict__ wgT) {
  int i = blockIdx.x * 256 + threadIdx.x;          // 2 x 131072
  int seg = i >> 17;
  int idx = i & 131071;
  int k = idx & 511, j = idx >> 9;                 // dst [256][512] <- src [512][256]
  const float* src = seg ? Wg : Wl;
  unsigned short* dst = seg ? wgT : wlT;
  dst[idx] = f2b(src[(size_t)k * 256 + j]);
}

// ---------------- merged input/h0 converts ----------------
__global__ void k_prep_x(const float* __restrict__ input, const float* __restrict__ h0,
                         unsigned short* __restrict__ inb, unsigned short* __restrict__ h0b) {
  int i = blockIdx.x * 256 + threadIdx.x;          // 2 x 2^20
  int seg = i >> 20;
  int idx = i & 1048575;
  if (seg) h0b[idx] = f2b(h0[idx]);
  else     inb[idx] = f2b(input[idx]);
}

// ---------------- copy (float4) ----------------
__global__ void k_copy4(const float4* __restrict__ src, float4* __restrict__ dst, int n4) {
  int idx = blockIdx.x * 256 + threadIdx.x;
  if (idx < n4) dst[idx] = src[idx];
}

// ================= CSR build (per-launch) + gather aggregation =================
__global__ void k_zero(int* __restrict__ p, int n) {
  int i = blockIdx.x * 256 + threadIdx.x;
  if (i < n) p[i] = 0;
}
__global__ void k_hist(const int* __restrict__ adj, int* __restrict__ cnt) {
  int e = blockIdx.x * 256 + threadIdx.x;
  atomicAdd(&cnt[adj[E_ + e]], 1);
}
__global__ __launch_bounds__(1024) void k_scan(const int* __restrict__ cnt,
                                               int* __restrict__ off, int* __restrict__ cur) {
  __shared__ int ps[1024];
  int tid = threadIdx.x;
  int base = tid * 4;
  int a0 = cnt[base], a1 = cnt[base + 1], a2 = cnt[base + 2], a3 = cnt[base + 3];
  int tsum = a0 + a1 + a2 + a3;
  ps[tid] = tsum;
  __syncthreads();
  for (int st = 1; st < 1024; st <<= 1) {
    int v = (tid >= st) ? ps[tid - st] : 0;
    __syncthreads();
    ps[tid] += v;
    __syncthreads();
  }
  int excl = ps[tid] - tsum;
  int o0 = excl, o1 = excl + a0, o2 = o1 + a1, o3 = o2 + a2;
  off[base] = o0; off[base + 1] = o1; off[base + 2] = o2; off[base + 3] = o3;
  cur[base] = o0; cur[base + 1] = o1; cur[base + 2] = o2; cur[base + 3] = o3;
  if (tid == 1023) off[4096] = o3 + a3;
}
__global__ void k_bucket(const int* __restrict__ adj, int* __restrict__ cur,
                         int* __restrict__ perm) {
  int e = blockIdx.x * 256 + threadIdx.x;
  int p = atomicAdd(&cur[adj[E_ + e]], 1);
  perm[p] = e;
}
// Gather with the lin fold: xout[n] = x[n] + sum_e w*x[src]
//   + (sum_e w*dmap[e]) @ lin_w^T + (sum_e w)*lin_b     -- eab never read.
// Lanes 0..15 accumulate dsum[16]/wsum alongside the x gather; one 16-wide dot
// per thread at the end (lin_w 16KB, L2-hot). Exact f32 fold (fewer roundings
// than the old bf16-eab path).
__global__ __launch_bounds__(256) void k_gather(
    const float* __restrict__ x, const int* __restrict__ adj,
    const float* __restrict__ dmap, const float* __restrict__ nrm,
    const float* __restrict__ lin_w, const float* __restrict__ lin_b,
    const int* __restrict__ off, const int* __restrict__ perm,
    float* __restrict__ xout) {
  __shared__ float sds[17];
  int n = blockIdx.x, t = threadIdx.x;
  int beg = off[n], end = off[n + 1];
  float acc = x[(size_t)n * D_ + t];
  float ds = 0.f, ws = 0.f;
  int i = beg;
  for (; i + 1 < end; i += 2) {
    int e0 = perm[i], e1 = perm[i + 1];
    int s0 = adj[e0], s1 = adj[e1];
    float w0 = nrm[e0], w1 = nrm[e1];
    acc += w0 * x[(size_t)s0 * D_ + t] + w1 * x[(size_t)s1 * D_ + t];
    if (t < DIN_) {
      ds += w0 * dmap[(size_t)e0 * DIN_ + t] + w1 * dmap[(size_t)e1 * DIN_ + t];
      ws += w0 + w1;
    }
  }
  if (i < end) {
    int e0 = perm[i];
    int s0 = adj[e0];
    float w0 = nrm[e0];
    acc += w0 * x[(size_t)s0 * D_ + t];
    if (t < DIN_) {
      ds += w0 * dmap[(size_t)e0 * DIN_ + t];
      ws += w0;
    }
  }
  if (t < DIN_) { sds[t] = ds; if (t == 0) sds[16] = ws; }
  __syncthreads();
  float ex = sds[16] * lin_b[t];
  const float4* lw = (const float4*)(lin_w + (size_t)t * DIN_);
  float4 l0 = lw[0], l1 = lw[1], l2 = lw[2], l3 = lw[3];
  ex += sds[0] * l0.x + sds[1] * l0.y + sds[2] * l0.z + sds[3] * l0.w;
  ex += sds[4] * l1.x + sds[5] * l1.y + sds[6] * l1.z + sds[7] * l1.w;
  ex += sds[8] * l2.x + sds[9] * l2.y + sds[10] * l2.z + sds[11] * l2.w;
  ex += sds[12] * l3.x + sds[13] * l3.y + sds[14] * l3.z + sds[15] * l3.w;
  xout[(size_t)n * D_ + t] = acc + ex;
}

// ---------------- legacy scatter (fallback path) ----------------
__global__ __launch_bounds__(256) void k_scatter(
    const float* __restrict__ x, const int* __restrict__ adj,
    const float* __restrict__ dmap, const float* __restrict__ nrm,
    const float* __restrict__ lin_w, const float* __restrict__ lin_b,
    float* __restrict__ xout) {
  __shared__ float s_dm[4][DIN_];
  int te = threadIdx.x >> 6;
  int d4 = threadIdx.x & 63;
  int e  = blockIdx.x * 4 + te;
  if (d4 < DIN_) s_dm[te][d4] = dmap[(size_t)e * DIN_ + d4];
  __syncthreads();
  int vs = adj[e];
  int vd = adj[E_ + e];
  float w = nrm[e];
  int d = d4 * 4;
  float4 xs = *(const float4*)(x + (size_t)vs * D_ + d);
  float ea[4];
#pragma unroll
  for (int q = 0; q < 4; q++) {
    const float* lw = lin_w + (size_t)(d + q) * DIN_;
    float acc = lin_b[d + q];
#pragma unroll
    for (int k = 0; k < DIN_; k++) acc += s_dm[te][k] * lw[k];
    ea[q] = acc;
  }
  float* op = xout + (size_t)vd * D_ + d;
  atomicAdd(op + 0, w * (xs.x + ea[0]));
  atomicAdd(op + 1, w * (xs.y + ea[1]));
  atomicAdd(op + 2, w * (xs.z + ea[2]));
  atomicAdd(op + 3, w * (xs.w + ea[3]));
}

// ---------------- C[M,N] = A[M,K] @ B[N,K]^T + bias (fp32, fallback) ----------------
__global__ __launch_bounds__(256) void k_gemm_bt(
    const float* __restrict__ A, const float* __restrict__ B,
    const float* __restrict__ bias, float* __restrict__ C,
    int M, int Nn, int K) {
  __shared__ float sA[16][68];
  __shared__ float sB[16][68];
  int bm = blockIdx.y * 64, bn = blockIdx.x * 64;
  int tid = threadIdx.x;
  int tr = tid >> 4, tc = tid & 15;
  float acc[4][4] = {};
  for (int k0 = 0; k0 < K; k0 += 16) {
    for (int i = tid; i < 1024; i += 256) {
      int r = i >> 4, c = i & 15;
      sA[c][r] = A[(size_t)(bm + r) * K + k0 + c];
      sB[c][r] = B[(size_t)(bn + r) * K + k0 + c];
    }
    __syncthreads();
#pragma unroll
    for (int kk = 0; kk < 16; kk++) {
      float av[4], bv[4];
#pragma unroll
      for (int i = 0; i < 4; i++) av[i] = sA[kk][tr * 4 + i];
#pragma unroll
      for (int j = 0; j < 4; j++) bv[j] = sB[kk][tc * 4 + j];
#pragma unroll
      for (int i = 0; i < 4; i++)
#pragma unroll
        for (int j = 0; j < 4; j++) acc[i][j] += av[i] * bv[j];
    }
    __syncthreads();
  }
#pragma unroll
  for (int i = 0; i < 4; i++) {
    int r = bm + tr * 4 + i;
#pragma unroll
    for (int j = 0; j < 4; j++) {
      int c = bn + tc * 4 + j;
      C[(size_t)r * Nn + c] = acc[i][j] + bias[c];
    }
  }
}

// ---------------- qkv proj via MFMA: bf16 in, fp32 qkv out ----------------
__global__ __launch_bounds__(256) void k_qkv_mfma(
    const unsigned short* __restrict__ inb, const unsigned short* __restrict__ wqb,
    const float* __restrict__ ipb, float* __restrict__ qkv) {
  __shared__ unsigned short sA[128][72];
  __shared__ unsigned short sB[128][72];
  const int b   = blockIdx.x;
  const int j0  = (b % 6) * 128;
  const int m0  = (b / 6) * 128;
  const int tid = threadIdx.x;
  const int lane = tid & 63, wv = tid >> 6;
  const int r16  = lane & 15, quad = lane >> 4;
  const int sr   = tid >> 1, sh = (tid & 1) * 32;

  const unsigned short* ra = inb + (size_t)(m0 + sr) * D_;
  const unsigned short* rb = wqb + (size_t)(j0 + sr) * D_;

  const f32x4 zz = {0.f, 0.f, 0.f, 0.f};
  f32x4 acc[2][8];
#pragma unroll
  for (int m = 0; m < 2; ++m)
#pragma unroll
    for (int n = 0; n < 8; ++n) acc[m][n] = zz;

  for (int ki = 0; ki < 4; ++ki) {
    __syncthreads();
    {
      const uint4* s    = (const uint4*)(ra + ki * 64 + sh);
      const uint4* bsrc = (const uint4*)(rb + ki * 64 + sh);
      uint4* da = (uint4*)&sA[sr][sh];
      uint4* db = (uint4*)&sB[sr][sh];
#pragma unroll
      for (int i = 0; i < 4; ++i) { da[i] = s[i]; db[i] = bsrc[i]; }
    }
    __syncthreads();
#pragma unroll
    for (int kk = 0; kk < 2; ++kk) {
      bf16_8 a0 = frag16(&sA[wv * 32 + r16][kk * 32 + quad * 8]);
      bf16_8 a1 = frag16(&sA[wv * 32 + 16 + r16][kk * 32 + quad * 8]);
#pragma unroll
      for (int n = 0; n < 8; ++n) {
        bf16_8 bf = frag16(&sB[n * 16 + r16][kk * 32 + quad * 8]);
        acc[0][n] = __builtin_amdgcn_mfma_f32_16x16x32_bf16(a0, bf, acc[0][n], 0, 0, 0);
        acc[1][n] = __builtin_amdgcn_mfma_f32_16x16x32_bf16(a1, bf, acc[1][n], 0, 0, 0);
      }
    }
  }
#pragma unroll
  for (int m = 0; m < 2; ++m)
#pragma unroll
    for (int n = 0; n < 8; ++n) {
      int col = j0 + n * 16 + r16;
      float bb = ipb[col];
#pragma unroll
      for (int rg = 0; rg < 4; ++rg) {
        int row = m0 + wv * 32 + m * 16 + quad * 4 + rg;
        qkv[(size_t)row * D3_ + col] = acc[m][n][rg] + bb;
      }
    }
}

// ---------------- node GEMM: Pac = x_out @ [W1a | W1c]^T, bf16 [4096][1024] ----
// cols 0..511 = x_out @ W1a^T (w1 rows j, k 0..255)
// cols 512..1023 = x_out @ W1c^T (w1 row (col-512), k 512..767)
__global__ __launch_bounds__(256) void k_node_pac(
    const unsigned short* __restrict__ xbp, const unsigned short* __restrict__ wb1,
    unsigned short* __restrict__ Pac) {
  __shared__ unsigned short sA[128][72];
  __shared__ unsigned short sB[128][72];
  const int b    = blockIdx.x;          // 32 m-tiles x 8 j-tiles
  const int j0   = (b & 7) * 128;
  const int m0   = (b >> 3) * 128;
  const int side = j0 >> 9;             // 0: W1a, 1: W1c
  const int jr   = j0 - side * 512;
  const int tid  = threadIdx.x;
  const int lane = tid & 63, wv = tid >> 6;
  const int r16  = lane & 15, quad = lane >> 4;
  const int sr   = tid >> 1, sh = (tid & 1) * 32;

  const unsigned short* ra = xbp + (size_t)(m0 + sr) * D_;
  const unsigned short* rb = wb1 + (size_t)(jr + sr) * 768 + side * 512;

  const f32x4 zz = {0.f, 0.f, 0.f, 0.f};
  f32x4 acc[2][8];
#pragma unroll
  for (int m = 0; m < 2; ++m)
#pragma unroll
    for (int n = 0; n < 8; ++n) acc[m][n] = zz;

  for (int ki = 0; ki < 4; ++ki) {
    __syncthreads();
    {
      const uint4* s    = (const uint4*)(ra + ki * 64 + sh);
      const uint4* bsrc = (const uint4*)(rb + ki * 64 + sh);
      uint4* da = (uint4*)&sA[sr][sh];
      uint4* db = (uint4*)&sB[sr][sh];
#pragma unroll
      for (int i = 0; i < 4; ++i) { da[i] = s[i]; db[i] = bsrc[i]; }
    }
    __syncthreads();
#pragma unroll
    for (int kk = 0; kk < 2; ++kk) {
      bf16_8 a0 = frag16(&sA[wv * 32 + r16][kk * 32 + quad * 8]);
      bf16_8 a1 = frag16(&sA[wv * 32 + 16 + r16][kk * 32 + quad * 8]);
#pragma unroll
      for (int n = 0; n < 8; ++n) {
        bf16_8 bf = frag16(&sB[n * 16 + r16][kk * 32 + quad * 8]);
        acc[0][n] = __builtin_amdgcn_mfma_f32_16x16x32_bf16(a0, bf, acc[0][n], 0, 0, 0);
        acc[1][n] = __builtin_amdgcn_mfma_f32_16x16x32_bf16(a1, bf, acc[1][n], 0, 0, 0);
      }
    }
  }
#pragma unroll
  for (int m = 0; m < 2; ++m)
#pragma unroll
    for (int n = 0; n < 8; ++n) {
      int col = j0 + n * 16 + r16;
#pragma unroll
      for (int rg = 0; rg < 4; ++rg) {
        int row = m0 + wv * 32 + m * 16 + quad * 4 + rg;
        Pac[(size_t)row * 1024 + col] = f2b(acc[m][n][rg]);
      }
    }
}

// ---------------- out_proj via MFMA: hgl = attob @ opwb^T + opb; hgb = bf16 ----
__global__ __launch_bounds__(256) void k_outproj_mfma(
    const unsigned short* __restrict__ attob, const unsigned short* __restrict__ opwb,
    const float* __restrict__ opb, float* __restrict__ hgl,
    unsigned short* __restrict__ hgb) {
  __shared__ unsigned short sA[128][72];
  __shared__ unsigned short sB[128][72];
  const int b   = blockIdx.x;
  const int j0  = (b & 1) * 128;
  const int m0  = (b >> 1) * 128;
  const int tid = threadIdx.x;
  const int lane = tid & 63, wv = tid >> 6;
  const int r16  = lane & 15, quad = lane >> 4;
  const int sr   = tid >> 1, sh = (tid & 1) * 32;

  const unsigned short* ra = attob + (size_t)(m0 + sr) * D_;
  const unsigned short* rb = opwb + (size_t)(j0 + sr) * D_;

  const f32x4 zz = {0.f, 0.f, 0.f, 0.f};
  f32x4 acc[2][8];
#pragma unroll
  for (int m = 0; m < 2; ++m)
#pragma unroll
    for (int n = 0; n < 8; ++n) acc[m][n] = zz;

  for (int ki = 0; ki < 4; ++ki) {
    __syncthreads();
    {
      const uint4* s    = (const uint4*)(ra + ki * 64 + sh);
      const uint4* bsrc = (const uint4*)(rb + ki * 64 + sh);
      uint4* da = (uint4*)&sA[sr][sh];
      uint4* db = (uint4*)&sB[sr][sh];
#pragma unroll
      for (int i = 0; i < 4; ++i) { da[i] = s[i]; db[i] = bsrc[i]; }
    }
    __syncthreads();
#pragma unroll
    for (int kk = 0; kk < 2; ++kk) {
      bf16_8 a0 = frag16(&sA[wv * 32 + r16][kk * 32 + quad * 8]);
      bf16_8 a1 = frag16(&sA[wv * 32 + 16 + r16][kk * 32 + quad * 8]);
#pragma unroll
      for (int n = 0; n < 8; ++n) {
        bf16_8 bf = frag16(&sB[n * 16 + r16][kk * 32 + quad * 8]);
        acc[0][n] = __builtin_amdgcn_mfma_f32_16x16x32_bf16(a0, bf, acc[0][n], 0, 0, 0);
        acc[1][n] = __builtin_amdgcn_mfma_f32_16x16x32_bf16(a1, bf, acc[1][n], 0, 0, 0);
      }
    }
  }
#pragma unroll
  for (int m = 0; m < 2; ++m)
#pragma unroll
    for (int n = 0; n < 8; ++n) {
      int col = j0 + n * 16 + r16;
      float bb = opb[col];
#pragma unroll
      for (int rg = 0; rg < 4; ++rg) {
        int row = m0 + wv * 32 + m * 16 + quad * 4 + rg;
        float v = acc[m][n][rg] + bb;
        size_t idx = (size_t)row * D_ + col;
        hgl[idx] = v;
        hgb[idx] = f2b(v);
      }
    }
}

// ---------------- final combine via MFMA ----------------
__global__ __launch_bounds__(256) void k_final_mfma(
    const unsigned short* __restrict__ xbp, const unsigned short* __restrict__ h0b,
    const unsigned short* __restrict__ hgb,
    const unsigned short* __restrict__ wlT, const unsigned short* __restrict__ wgT,
    const float* __restrict__ hl, const float* __restrict__ hg, const float* __restrict__ h0,
    const float* __restrict__ alpha_p, const void* lamda_p, const void* l_p,
    float* __restrict__ out) {
  __shared__ unsigned short sA[128][72];
  __shared__ unsigned short sB[128][72];
  const int b   = blockIdx.x;
  const int j0  = (b & 1) * 128;
  const int m0  = (b >> 1) * 128;
  const int tid = threadIdx.x;
  const int lane = tid & 63, wv = tid >> 6;
  const int r16  = lane & 15, quad = lane >> 4;
  const int sr   = tid >> 1, sh = (tid & 1) * 32;

  const f32x4 zz = {0.f, 0.f, 0.f, 0.f};
  f32x4 acc[2][8];
#pragma unroll
  for (int m = 0; m < 2; ++m)
#pragma unroll
    for (int n = 0; n < 8; ++n) acc[m][n] = zz;

  const size_t arow = (size_t)(m0 + sr) * D_;
  const size_t brow = (size_t)(j0 + sr) * 512;

  for (int ki = 0; ki < 16; ++ki) {
    __syncthreads();
    {
      const int gc = ki * 64 + sh;
      const unsigned short* ap =
          (gc < 256) ? xbp + arow + gc
        : (gc < 512) ? h0b + arow + (gc - 256)
        : (gc < 768) ? hgb + arow + (gc - 512)
                     : h0b + arow + (gc - 768);
      const unsigned short* bp = (gc < 512) ? wlT + brow + gc : wgT + brow + (gc - 512);
      const uint4* s    = (const uint4*)ap;
      const uint4* bsrc = (const uint4*)bp;
      uint4* da = (uint4*)&sA[sr][sh];
      uint4* db = (uint4*)&sB[sr][sh];
#pragma unroll
      for (int i = 0; i < 4; ++i) { da[i] = s[i]; db[i] = bsrc[i]; }
    }
    __syncthreads();
#pragma unroll
    for (int kk = 0; kk < 2; ++kk) {
      bf16_8 a0 = frag16(&sA[wv * 32 + r16][kk * 32 + quad * 8]);
      bf16_8 a1 = frag16(&sA[wv * 32 + 16 + r16][kk * 32 + quad * 8]);
#pragma unroll
      for (int n = 0; n < 8; ++n) {
        bf16_8 bf = frag16(&sB[n * 16 + r16][kk * 32 + quad * 8]);
        acc[0][n] = __builtin_amdgcn_mfma_f32_16x16x32_bf16(a0, bf, acc[0][n], 0, 0, 0);
        acc[1][n] = __builtin_amdgcn_mfma_f32_16x16x32_bf16(a1, bf, acc[1][n], 0, 0, 0);
      }
    }
  }
  float theta = fminf(1.f, logf(scalar_as_float(lamda_p) / scalar_as_float(l_p) + 1.f));
  float a = alpha_p[0];
  float omt = 1.f - theta;
#pragma unroll
  for (int m = 0; m < 2; ++m)
#pragma unroll
    for (int n = 0; n < 8; ++n) {
      int col = j0 + n * 16 + r16;
#pragma unroll
      for (int rg = 0; rg < 4; ++rg) {
        int row = m0 + wv * 32 + m * 16 + quad * 4 + rg;
        size_t idx = (size_t)row * D_ + col;
        out[idx] = theta * acc[m][n][rg] +
                   omt * ((1.f - a) * (hl[idx] + hg[idx]) + 2.f * a * h0[idx]);
      }
    }
}

// ---------------- qkv split: fp32 [N,768] -> bf16 Qb/Kb [h][n][128] ----------------
__global__ void k_qk2b(const float* __restrict__ qkv,
                       unsigned short* __restrict__ Qb, unsigned short* __restrict__ Kb) {
  int off = (blockIdx.x * 256 + threadIdx.x) * 8;   // over N*512
  int n = off >> 9, c = off & 511;
  const float* src = qkv + (size_t)n * D3_ + c;     // Q cols 0..255, K cols 256..511
  float4 a = *(const float4*)src;
  float4 b = *(const float4*)(src + 4);
  uint4 p = {pack2(f2b(a.x), f2b(a.y)), pack2(f2b(a.z), f2b(a.w)),
             pack2(f2b(b.x), f2b(b.y)), pack2(f2b(b.z), f2b(b.w))};
  int cc = c & 255;
  int hh = cc >> 7, d = cc & 127;
  unsigned short* dst = (c < 256 ? Qb : Kb) + (size_t)hh * N_ * HD_ + (size_t)n * HD_ + d;
  *(uint4*)dst = p;
}

// ---------------- V transpose: fp32 qkv V-cols -> bf16 Vt [h][128][N] ----------------
__global__ __launch_bounds__(256) void k_v2t(const float* __restrict__ qkv,
                                             unsigned short* __restrict__ Vt) {
  __shared__ unsigned short sv[64][136];
  int h = blockIdx.y;
  int n0 = blockIdx.x * 64;
  int tid = threadIdx.x;
#pragma unroll
  for (int it = 0; it < 4; ++it) {
    int off = (tid + it * 256) * 8;
    int r = off >> 7, d = off & 127;
    const float* src = qkv + (size_t)(n0 + r) * D3_ + 2 * D_ + h * HD_ + d;
    float4 a = *(const float4*)src;
    float4 b = *(const float4*)(src + 4);
    uint4 p = {pack2(f2b(a.x), f2b(a.y)), pack2(f2b(a.z), f2b(a.w)),
               pack2(f2b(b.x), f2b(b.y)), pack2(f2b(b.z), f2b(b.w))};
    *(uint4*)&sv[r][d] = p;
  }
  __syncthreads();
#pragma unroll
  for (int it = 0; it < 4; ++it) {
    int off = (tid + it * 256) * 8;
    int d = off >> 6, k = off & 63;
    unsigned short t[8];
#pragma unroll
    for (int j = 0; j < 8; ++j) t[j] = sv[k + j][d];
    uint4 p = {pack2(t[0], t[1]), pack2(t[2], t[3]),
               pack2(t[4], t[5]), pack2(t[6], t[7])};
    *(uint4*)(Vt + (size_t)h * HD_ * N_ + (size_t)d * N_ + n0 + k) = p;
  }
}

// ---------------- MFMA flash attention, H=2, HD=128 (dual fp32+bf16 out) ----------------
__global__ __launch_bounds__(256) void k_attn_mfma(
    const unsigned short* __restrict__ Qb, const unsigned short* __restrict__ Kb,
    const unsigned short* __restrict__ Vt, float* __restrict__ o_out,
    unsigned short* __restrict__ ob) {
  __shared__ unsigned short sK[64][136];   // keys x dims (+8 pad)
  __shared__ unsigned short sV[128][72];   // dims x keys (+8 pad)
  __shared__ float          sS[16][68];    // scores
  __shared__ unsigned short sP[16][72];    // probs bf16 (A-frag layout)
  __shared__ float sm[16], sl[16], sa[16];

  const int tid  = threadIdx.x;
  const int h    = blockIdx.y;
  const int q0   = blockIdx.x * 16;
  const int lane = tid & 63;
  const int wv   = tid >> 6;
  const int r16  = lane & 15;
  const int quad = lane >> 4;

  bf16_8 qf[4];
#pragma unroll
  for (int kk = 0; kk < 4; ++kk)
    qf[kk] = frag16(Qb + (size_t)h * N_ * HD_ + (size_t)(q0 + r16) * HD_ + kk * 32 + quad * 8);

  if (tid < 16) { sm[tid] = -1e30f; sl[tid] = 0.f; }

  const f32x4 zz = {0.f, 0.f, 0.f, 0.f};
  f32x4 o0 = zz, o1 = zz;

  const unsigned short* Kh = Kb + (size_t)h * N_ * HD_;
  const unsigned short* Vh = Vt + (size_t)h * HD_ * N_;

  for (int c0 = 0; c0 < N_; c0 += 64) {
    __syncthreads();
#pragma unroll
    for (int it = 0; it < 4; ++it) {
      int off = (tid + it * 256) * 8;
      int key = off >> 7, d = off & 127;
      *(uint4*)&sK[key][d] = *(const uint4*)(Kh + (size_t)(c0 + key) * HD_ + d);
    }
#pragma unroll
    for (int it = 0; it < 4; ++it) {
      int off = (tid + it * 256) * 8;
      int d = off >> 6, k = off & 63;
      *(uint4*)&sV[d][k] = *(const uint4*)(Vh + (size_t)d * N_ + c0 + k);
    }
    __syncthreads();
    f32x4 s = zz;
#pragma unroll
    for (int kk = 0; kk < 4; ++kk) {
      bf16_8 bf = frag16(&sK[wv * 16 + r16][kk * 32 + quad * 8]);
      s = __builtin_amdgcn_mfma_f32_16x16x32_bf16(qf[kk], bf, s, 0, 0, 0);
    }
    const float sc = 0.08838834764831845f;   // 1/sqrt(128)
#pragma unroll
    for (int r = 0; r < 4; ++r)
      sS[quad * 4 + r][wv * 16 + r16] = s[r] * sc;
    __syncthreads();
    {
      int row = tid >> 4, i = tid & 15;
      float4 v = *(const float4*)&sS[row][i * 4];
      float mx = fmaxf(fmaxf(v.x, v.y), fmaxf(v.z, v.w));
#pragma unroll
      for (int m = 1; m <= 8; m <<= 1) mx = fmaxf(mx, __shfl_xor(mx, m));
      float mo = sm[row];
      float mn = fmaxf(mo, mx);
      float p0 = __expf(v.x - mn), p1 = __expf(v.y - mn);
      float p2 = __expf(v.z - mn), p3 = __expf(v.w - mn);
      float ps = p0 + p1 + p2 + p3;
#pragma unroll
      for (int m = 1; m <= 8; m <<= 1) ps += __shfl_xor(ps, m);
      uint2 pk = {pack2(f2b(p0), f2b(p1)), pack2(f2b(p2), f2b(p3))};
      *(uint2*)&sP[row][i * 4] = pk;
      if (i == 0) {
        float al = __expf(mo - mn);
        sl[row] = sl[row] * al + ps;
        sm[row] = mn;
        sa[row] = al;
      }
    }
    __syncthreads();
    {
      float al0 = sa[quad * 4 + 0], al1 = sa[quad * 4 + 1];
      float al2 = sa[quad * 4 + 2], al3 = sa[quad * 4 + 3];
      o0[0] *= al0; o0[1] *= al1; o0[2] *= al2; o0[3] *= al3;
      o1[0] *= al0; o1[1] *= al1; o1[2] *= al2; o1[3] *= al3;
#pragma unroll
      for (int kk = 0; kk < 2; ++kk) {
        bf16_8 pa = frag16(&sP[r16][kk * 32 + quad * 8]);
        bf16_8 v0 = frag16(&sV[wv * 32 + r16][kk * 32 + quad * 8]);
        bf16_8 v1 = frag16(&sV[wv * 32 + 16 + r16][kk * 32 + quad * 8]);
        o0 = __builtin_amdgcn_mfma_f32_16x16x32_bf16(pa, v0, o0, 0, 0, 0);
        o1 = __builtin_amdgcn_mfma_f32_16x16x32_bf16(pa, v1, o1, 0, 0, 0);
      }
    }
  }
  {
    float i0 = 1.f / sl[quad * 4 + 0], i1 = 1.f / sl[quad * 4 + 1];
    float i2 = 1.f / sl[quad * 4 + 2], i3 = 1.f / sl[quad * 4 + 3];
    float vv[8];
    vv[0] = o0[0] * i0; vv[1] = o0[1] * i1; vv[2] = o0[2] * i2; vv[3] = o0[3] * i3;
    vv[4] = o1[0] * i0; vv[5] = o1[1] * i1; vv[6] = o1[2] * i2; vv[7] = o1[3] * i3;
#pragma unroll
    for (int g = 0; g < 2; ++g)
#pragma unroll
      for (int rg = 0; rg < 4; ++rg) {
        size_t idx = (size_t)(q0 + quad * 4 + rg) * D_ + h * HD_ + wv * 32 + g * 16 + r16;
        float v = vv[g * 4 + rg];
        o_out[idx] = v;
        ob[idx] = f2b(v);
      }
  }
}

// ---------------- final combine (fp32, fallback) ----------------
__global__ __launch_bounds__(256) void k_final(
    const float* __restrict__ hl, const float* __restrict__ hg, const float* __restrict__ h0,
    const float* __restrict__ Wl, const float* __restrict__ Wg,
    const float* __restrict__ alpha_p, const void* lamda_p, const void* l_p,
    float* __restrict__ out) {
  __shared__ float sA[16][68];
  __shared__ float sB[16][68];
  float theta = fminf(1.f, logf(scalar_as_float(lamda_p) / scalar_as_float(l_p) + 1.f));
  float a = alpha_p[0];
  int bm = blockIdx.y * 64, bn = blockIdx.x * 64;
  int tid = threadIdx.x, tr = tid >> 4, tc = tid & 15;
  float acc[4][4] = {};
  for (int k0 = 0; k0 < 1024; k0 += 16) {
    for (int i = tid; i < 1024; i += 256) {
      int r = i >> 4, c = i & 15;
      int k = k0 + c;
      const float* src = (k < 256) ? hl : (k < 512) ? h0 : (k < 768) ? hg : h0;
      sA[c][r] = src[(size_t)(bm + r) * 256 + (k & 255)];
    }
    for (int i = tid; i < 1024; i += 256) {
      int kk = i >> 6, j = i & 63;
      int k = k0 + kk;
      const float* Bp = (k < 512) ? (Wl + (size_t)k * 256) : (Wg + (size_t)(k - 512) * 256);
      sB[kk][j] = Bp[bn + j];
    }
    __syncthreads();
#pragma unroll
    for (int kk = 0; kk < 16; kk++) {
      float av[4], bv[4];
#pragma unroll
      for (int i = 0; i < 4; i++) av[i] = sA[kk][tr * 4 + i];
#pragma unroll
      for (int j = 0; j < 4; j++) bv[j] = sB[kk][tc * 4 + j];
#pragma unroll
      for (int i = 0; i < 4; i++)
#pragma unroll
        for (int j = 0; j < 4; j++) acc[i][j] += av[i] * bv[j];
    }
    __syncthreads();
  }
  float omt = 1.f - theta;
#pragma unroll
  for (int i = 0; i < 4; i++) {
    int r = bm + tr * 4 + i;
#pragma unroll
    for (int j = 0; j < 4; j++) {
      int c = bn + tc * 4 + j;
      size_t idx = (size_t)r * 256 + c;
      out[idx] = theta * acc[i][j] + omt * ((1.f - a) * (hl[idx] + hg[idx]) + 2.f * a * h0[idx]);
    }
  }
}

// ================= decomposed edge-MLP stage 1, lin-folded (fast path) =======
// t1[e][c] = gelu( (dmap[e] @ M^T)[c] + Pa[src(e)][c] + Pc[dst(e)][c] + cb[c] )
// The old K=256 GEMM over eab is ONE zero-padded K=16 MFMA per fragment.
// No staging, no barriers; LDS = 17 KB wave-private bounce only.
__global__ __launch_bounds__(256, 4) void k_mlp_gemm1c(
    const float* __restrict__ dmap, const int* __restrict__ adj,
    const unsigned short* __restrict__ Pac, const unsigned short* __restrict__ Mb,
    const float* __restrict__ cbv, unsigned short* __restrict__ t1) {
  __shared__ unsigned short shm[8704];    // 17 KB: 4 waves x [16][136] bounce
  const int b    = blockIdx.x;
  const int c0   = (b >> 10) * 128;       // col quarter of t1's 512 (quarter-major)
  const int e0   = (b & 1023) * 128;
  const int tid  = threadIdx.x;
  const int lane = tid & 63, wv = tid >> 6;
  const int r16  = lane & 15, quad = lane >> 4;

  const uint4 z4 = make_uint4(0u, 0u, 0u, 0u);
  // A-frags: dmap rows for this wave's two 16-edge tiles (zero-padded K 16->32)
  bf16_8 af[2];
#pragma unroll
  for (int m = 0; m < 2; ++m) {
    uint4 p = z4;
    if (quad < 2) {
      const int edge = e0 + wv * 32 + m * 16 + r16;
      const float4* dp = (const float4*)(dmap + (size_t)edge * DIN_ + quad * 8);
      float4 a = dp[0], bq = dp[1];
      p = make_uint4(pack2(f2b(a.x), f2b(a.y)), pack2(f2b(a.z), f2b(a.w)),
                     pack2(f2b(bq.x), f2b(bq.y)), pack2(f2b(bq.z), f2b(bq.w)));
    }
    af[m] = __builtin_bit_cast(bf16_8, p);
  }

  const f32x4 zz = {0.f, 0.f, 0.f, 0.f};
  f32x4 acc[2][8];
#pragma unroll
  for (int n = 0; n < 8; ++n) {
    uint4 mv = z4;
    if (quad < 2)
      mv = *(const uint4*)(Mb + (size_t)(c0 + n * 16 + r16) * DIN_ + quad * 8);
    bf16_8 bf = __builtin_bit_cast(bf16_8, mv);
    acc[0][n] = __builtin_amdgcn_mfma_f32_16x16x32_bf16(af[0], bf, zz, 0, 0, 0);
    acc[1][n] = __builtin_amdgcn_mfma_f32_16x16x32_bf16(af[1], bf, zz, 0, 0, 0);
  }

  // ---- epilogue: per-wave bf16 bounce [16][136]; add gathered Pa/Pc; gelu ----
  unsigned short* reg = shm + wv * 2176;    // 16*136 shorts = 4352 B/wave
#pragma unroll
  for (int m = 0; m < 2; ++m) {
#pragma unroll
    for (int n = 0; n < 8; ++n)
#pragma unroll
      for (int rg = 0; rg < 4; ++rg)
        reg[(quad * 4 + rg) * 136 + n * 16 + r16] = f2b(acc[m][n][rg]);
    // wave-private scratch: in-wave LDS ordering suffices (no barrier)
#pragma unroll
    for (int it = 0; it < 4; ++it) {
      int flat = it * 64 + lane;
      int row = flat >> 4;                  // 0..15
      int g   = flat & 15;                  // col group -> 8 cols (128/8 = 16 groups)
      int er  = e0 + wv * 32 + m * 16 + row;
      int vs  = adj[er];
      int vd  = adj[E_ + er];
      int c   = c0 + g * 8;                 // global col in [0,512)
      uint4 midq = *(const uint4*)&reg[row * 136 + g * 8];
      uint4 paq  = *(const uint4*)(Pac + (size_t)vs * 1024 + c);
      uint4 pcq  = *(const uint4*)(Pac + (size_t)vd * 1024 + 512 + c);
      float4 ba = *(const float4*)(cbv + c);
      float4 bb = *(const float4*)(cbv + c + 4);
      const unsigned int mv[4] = {midq.x, midq.y, midq.z, midq.w};
      const unsigned int pv[4] = {paq.x, paq.y, paq.z, paq.w};
      const unsigned int cv[4] = {pcq.x, pcq.y, pcq.z, pcq.w};
      const float bl[8] = {ba.x, ba.y, ba.z, ba.w, bb.x, bb.y, bb.z, bb.w};
      unsigned short us[8];
#pragma unroll
      for (int j = 0; j < 8; ++j) {
        unsigned short mw = (j & 1) ? (unsigned short)(mv[j >> 1] >> 16)
                                    : (unsigned short)(mv[j >> 1] & 0xffffu);
        unsigned short pw = (j & 1) ? (unsigned short)(pv[j >> 1] >> 16)
                                    : (unsigned short)(pv[j >> 1] & 0xffffu);
        unsigned short cw = (j & 1) ? (unsigned short)(cv[j >> 1] >> 16)
                                    : (unsigned short)(cv[j >> 1] & 0xffffu);
        float v = b2f(mw) + b2f(pw) + b2f(cw) + bl[j];
        us[j] = f2b(gelu_fast(v));
      }
      uint4 ov = make_uint4(pack2(us[0], us[1]), pack2(us[2], us[3]),
                            pack2(us[4], us[5]), pack2(us[6], us[7]));
      ntstore16(&t1[(size_t)er * 512 + c], ov);
    }
  }
}

// GEMM2+3 fused: t1[E,512] @ wb2^T -> gelu -> t2 (LDS only) -> @ wb3^T -> dmo.
__global__ __launch_bounds__(256, 2) void k_mlp_gemm23(
    const unsigned short* __restrict__ t1, const unsigned short* __restrict__ wb2,
    const float* __restrict__ b2, const unsigned short* __restrict__ wb3,
    const float* __restrict__ b3, float* __restrict__ dmo) {
  __shared__ unsigned short shm[24576];   // 48 KB: lA [0,8192) lB [8192,24576)
  unsigned short* lA = shm;
  unsigned short* lB = shm + 8192;
  const int e0   = blockIdx.x * 128;
  const int tid  = threadIdx.x;
  const int lane = tid & 63, wv = tid >> 6;
  const int r16  = lane & 15, quad = lane >> 4;

  const int row0 = e0 + wv * 32 + r16;
  const int row1 = row0 + 16;
  const unsigned short* pa0 = t1 + (size_t)row0 * 512 + quad * 8;
  const unsigned short* pa1 = t1 + (size_t)row1 * 512 + quad * 8;

  const f32x4 zz = {0.f, 0.f, 0.f, 0.f};
  f32x4 acc[2][16];
#pragma unroll
  for (int m = 0; m < 2; ++m)
#pragma unroll
    for (int n = 0; n < 16; ++n) acc[m][n] = zz;

  for (int ki = 0; ki < 8; ++ki) {
    __syncthreads();
    {
#pragma unroll
      for (int kk = 0; kk < 2; ++kk) {
        gl2lds16(pa0 + ki * 64 + kk * 32, &lA[(wv * 4 + kk) * 512]);
        gl2lds16(pa1 + ki * 64 + kk * 32, &lA[(wv * 4 + 2 + kk) * 512]);
#pragma unroll
        for (int i = 0; i < 4; ++i) {
          int n = wv * 4 + i;
          gl2lds16(wb2 + (size_t)(n * 16 + r16) * 512 + ki * 64 + kk * 32 + quad * 8,
                   &lB[(n * 2 + kk) * 512]);
        }
      }
    }
    __builtin_amdgcn_s_waitcnt(0);
    __syncthreads();
#pragma unroll
    for (int kk = 0; kk < 2; ++kk) {
      bf16_8 a0 = frag16(&lA[(wv * 4 + kk) * 512 + lane * 8]);
      bf16_8 a1 = frag16(&lA[(wv * 4 + 2 + kk) * 512 + lane * 8]);
#pragma unroll
      for (int n = 0; n < 16; ++n) {
        bf16_8 bf = frag16(&lB[(n * 2 + kk) * 512 + lane * 8]);
        acc[0][n] = __builtin_amdgcn_mfma_f32_16x16x32_bf16(a0, bf, acc[0][n], 0, 0, 0);
        acc[1][n] = __builtin_amdgcn_mfma_f32_16x16x32_bf16(a1, bf, acc[1][n], 0, 0, 0);
      }
    }
  }
  // ---- epilogue: per-wave padded scratch [16][264]; two m-passes; gemm3 ----
  __syncthreads();   // all compute LDS reads done before reuse
  unsigned short* reg = shm + wv * 4224;   // 16*264 = 4224 shorts = 8448 B/wave
  float bb3 = b3[r16];
#pragma unroll
  for (int m = 0; m < 2; ++m) {
#pragma unroll
    for (int n = 0; n < 16; ++n) {
      float bb = b2[n * 16 + r16];
#pragma unroll
      for (int rg = 0; rg < 4; ++rg)
        reg[(quad * 4 + rg) * 264 + n * 16 + r16] = f2b(gelu_fast(acc[m][n][rg] + bb));
    }
    // wave-private scratch: in-wave LDS ordering suffices (no barrier)
    f32x4 acc3 = zz;
#pragma unroll
    for (int ks = 0; ks < 8; ++ks) {
      bf16_8 a = frag16(&reg[r16 * 264 + ks * 32 + quad * 8]);
      bf16_8 b = frag16(wb3 + (size_t)r16 * 256 + ks * 32 + quad * 8);
      acc3 = __builtin_amdgcn_mfma_f32_16x16x32_bf16(a, b, acc3, 0, 0, 0);
    }
#pragma unroll
    for (int rg = 0; rg < 4; ++rg)
      dmo[(size_t)(e0 + wv * 32 + m * 16 + quad * 4 + rg) * DIN_ + r16] = acc3[rg] + bb3;
  }
}

// ---------------- fused edge MLP (fallback path) ----------------
__global__ __launch_bounds__(256, 3) void k_edge_mlp_mfma(
    const float* __restrict__ xout, const int* __restrict__ adj,
    const float* __restrict__ dmap,
    const float* __restrict__ lin_w, const float* __restrict__ lin_b,
    const unsigned short* __restrict__ wb1, const float* __restrict__ b1,
    const unsigned short* __restrict__ wb2, const float* __restrict__ b2,
    const unsigned short* __restrict__ wb3, const float* __restrict__ b3,
    float* __restrict__ dmo) {
  __shared__ unsigned short sLo[8448];
  __shared__ unsigned short sT1[32][520];
  unsigned short (*sA)[136]  = (unsigned short(*)[136])sLo;
  unsigned short (*sT2)[264] = (unsigned short(*)[264])sLo;

  const int tid  = threadIdx.x;
  const int e0   = blockIdx.x * 32;
  const int lane = tid & 63;
  const int wv   = tid >> 6;
  const int r16  = lane & 15;
  const int quad = lane >> 4;

  const int sr = tid >> 3;
  const int t8 = tid & 7;
  const int se = e0 + sr;
  const int vsrc = adj[se];
  const int vdst = adj[E_ + se];

  float4 pf0, pf1, pf2, pf3;
  float4 dm0, dm1, dm2, dm3;
  {
    const float4* sp = (const float4*)(xout + (size_t)vsrc * D_ + t8 * 16);
    pf0 = sp[0]; pf1 = sp[1]; pf2 = sp[2]; pf3 = sp[3];
  }

  const f32x4 zz = {0.f, 0.f, 0.f, 0.f};
  f32x4 acc1[8][2];
#pragma unroll
  for (int i = 0; i < 8; ++i) { acc1[i][0] = zz; acc1[i][1] = zz; }

  for (int c = 0; c < 6; ++c) {
    const int k0 = c * 128;
    __syncthreads();
    {
      unsigned short tmp[16];
      if (c == 2 || c == 3) {
        int jb = (c - 2) * 128 + t8 * 16;
#pragma unroll
        for (int j = 0; j < 16; ++j) {
          const float4* lw = (const float4*)(lin_w + (size_t)(jb + j) * DIN_);
          float4 w0 = lw[0], w1 = lw[1], w2 = lw[2], w3 = lw[3];
          float acc = lin_b[jb + j];
          acc += dm0.x * w0.x + dm0.y * w0.y + dm0.z * w0.z + dm0.w * w0.w;
          acc += dm1.x * w1.x + dm1.y * w1.y + dm1.z * w1.z + dm1.w * w1.w;
          acc += dm2.x * w2.x + dm2.y * w2.y + dm2.z * w2.z + dm2.w * w2.w;
          acc += dm3.x * w3.x + dm3.y * w3.y + dm3.z * w3.z + dm3.w * w3.w;
          tmp[j] = f2b(acc);
        }
      } else {
        tmp[0]  = f2b(pf0.x); tmp[1]  = f2b(pf0.y); tmp[2]  = f2b(pf0.z); tmp[3]  = f2b(pf0.w);
        tmp[4]  = f2b(pf1.x); tmp[5]  = f2b(pf1.y); tmp[6]  = f2b(pf1.z); tmp[7]  = f2b(pf1.w);
        tmp[8]  = f2b(pf2.x); tmp[9]  = f2b(pf2.y); tmp[10] = f2b(pf2.z); tmp[11] = f2b(pf2.w);
        tmp[12] = f2b(pf3.x); tmp[13] = f2b(pf3.y); tmp[14] = f2b(pf3.z); tmp[15] = f2b(pf3.w);
      }
      unsigned short* dstp = &sA[sr][t8 * 16];
      uint4 q0v = {pack2(tmp[0], tmp[1]),   pack2(tmp[2], tmp[3]),
                   pack2(tmp[4], tmp[5]),   pack2(tmp[6], tmp[7])};
      uint4 q1v = {pack2(tmp[8], tmp[9]),   pack2(tmp[10], tmp[11]),
                   pack2(tmp[12], tmp[13]), pack2(tmp[14], tmp[15])};
      *(uint4*)(dstp) = q0v;
      *(uint4*)(dstp + 8) = q1v;
    }
    if (c == 0) {
      const float4* sp = (const float4*)(xout + (size_t)vsrc * D_ + 128 + t8 * 16);
      pf0 = sp[0]; pf1 = sp[1]; pf2 = sp[2]; pf3 = sp[3];
    } else if (c == 1) {
      const float4* dp = (const float4*)(dmap + (size_t)se * DIN_);
      dm0 = ntload4(dp); dm1 = ntload4(dp + 1); dm2 = ntload4(dp + 2); dm3 = ntload4(dp + 3);
    } else if (c == 3) {
      const float4* sp = (const float4*)(xout + (size_t)vdst * D_ + t8 * 16);
      pf0 = sp[0]; pf1 = sp[1]; pf2 = sp[2]; pf3 = sp[3];
    } else if (c == 4) {
      const float4* sp = (const float4*)(xout + (size_t)vdst * D_ + 128 + t8 * 16);
      pf0 = sp[0]; pf1 = sp[1]; pf2 = sp[2]; pf3 = sp[3];
    }
    __syncthreads();
#pragma unroll
    for (int kk = 0; kk < 4; ++kk) {
      bf16_8 a0 = frag16(&sA[r16][kk * 32 + quad * 8]);
      bf16_8 a1 = frag16(&sA[16 + r16][kk * 32 + quad * 8]);
#pragma unroll
      for (int i = 0; i < 8; ++i) {
        const unsigned short* bp =
            wb1 + (size_t)(wv * 128 + i * 16 + r16) * 768 + k0 + kk * 32 + quad * 8;
        bf16_8 bf = frag16(bp);
        acc1[i][0] = __builtin_amdgcn_mfma_f32_16x16x32_bf16(a0, bf, acc1[i][0], 0, 0, 0);
        acc1[i][1] = __builtin_amdgcn_mfma_f32_16x16x32_bf16(a1, bf, acc1[i][1], 0, 0, 0);
      }
    }
  }
#pragma unroll
  for (int i = 0; i < 8; ++i) {
    int col = wv * 128 + i * 16 + r16;
    float bb = b1[col];
#pragma unroll
    for (int r = 0; r < 4; ++r) {
      int row = quad * 4 + r;
      sT1[row][col] = f2b(gelu_exact(acc1[i][0][r] + bb));
      sT1[row + 16][col] = f2b(gelu_exact(acc1[i][1][r] + bb));
    }
  }
  __syncthreads();

  f32x4 acc2[4][2];
#pragma unroll
  for (int i = 0; i < 4; ++i) { acc2[i][0] = zz; acc2[i][1] = zz; }
#pragma unroll 4
  for (int ks = 0; ks < 16; ++ks) {
    bf16_8 a0 = frag16(&sT1[r16][ks * 32 + quad * 8]);
    bf16_8 a1 = frag16(&sT1[16 + r16][ks * 32 + quad * 8]);
#pragma unroll
    for (int i = 0; i < 4; ++i) {
      const unsigned short* bp =
          wb2 + (size_t)(wv * 64 + i * 16 + r16) * 512 + ks * 32 + quad * 8;
      bf16_8 bf = frag16(bp);
      acc2[i][0] = __builtin_amdgcn_mfma_f32_16x16x32_bf16(a0, bf, acc2[i][0], 0, 0, 0);
      acc2[i][1] = __builtin_amdgcn_mfma_f32_16x16x32_bf16(a1, bf, acc2[i][1], 0, 0, 0);
    }
  }
#pragma unroll
  for (int i = 0; i < 4; ++i) {
    int col = wv * 64 + i * 16 + r16;
    float bb = b2[col];
#pragma unroll
    for (int m = 0; m < 2; ++m)
#pragma unroll
      for (int r = 0; r < 4; ++r) {
        int row = m * 16 + quad * 4 + r;
        sT2[row][col] = f2b(gelu_exact(acc2[i][m][r] + bb));
      }
  }
  __syncthreads();

  if (wv < 2) {
    f32x4 acc3 = zz;
#pragma unroll
    for (int ks = 0; ks < 8; ++ks) {
      bf16_8 a = frag16(&sT2[wv * 16 + r16][ks * 32 + quad * 8]);
      bf16_8 b = frag16(wb3 + (size_t)r16 * 256 + ks * 32 + quad * 8);
      acc3 = __builtin_amdgcn_mfma_f32_16x16x32_bf16(a, b, acc3, 0, 0, 0);
    }
    float bb = b3[r16];
#pragma unroll
    for (int r = 0; r < 4; ++r) {
      int row = wv * 16 + quad * 4 + r;
      __builtin_nontemporal_store(acc3[r] + bb, &dmo[(size_t)(e0 + row) * DIN_ + r16]);
    }
  }
}

extern "C" void kernel_launch(void* const* d_in, const int* in_sizes, int n_in,
                              void* d_out, int out_size, void* d_ws, size_t ws_size,
                              hipStream_t stream) {
  const float* input = (const float*)d_in[0];
  const int*   adj   = (const int*)d_in[1];
  const float* h0    = (const float*)d_in[2];
  const void*  lamda = d_in[3];
  const float* alpha = (const float*)d_in[4];
  const void*  lll   = d_in[5];
  const float* dmap  = (const float*)d_in[6];
  const float* nrm   = (const float*)d_in[7];
  const float* Wl    = (const float*)d_in[8];
  const float* Wg    = (const float*)d_in[9];
  const float* lin_w = (const float*)d_in[10];
  const float* lin_b = (const float*)d_in[11];
  const float* w1    = (const float*)d_in[12];
  const float* b1    = (const float*)d_in[13];
  const float* w2    = (const float*)d_in[14];
  const float* b2    = (const float*)d_in[15];
  const float* w3    = (const float*)d_in[16];
  const float* b3    = (const float*)d_in[17];
  const float* ipw   = (const float*)d_in[18];
  const float* ipb   = (const float*)d_in[19];
  const float* opw   = (const float*)d_in[20];
  const float* opb   = (const float*)d_in[21];
  float* out = (float*)d_out;
  float* dmo = out + (size_t)N_ * D_;

  // ---- workspace layout ----
  float* ws   = (float*)d_ws;
  float* xout = ws;                               // N*D f32
  float* qkv  = xout + (size_t)N_ * D_;           // N*3D f32 (reused late as Pac)
  float* atto = qkv  + (size_t)N_ * 3 * D_;       // N*D f32
  float* hgl  = atto + (size_t)N_ * D_;           // N*D f32
  unsigned short* wb1 = (unsigned short*)(hgl + (size_t)N_ * D_);  // 512*768
  unsigned short* wb2 = wb1 + 512 * 768;          // 256*512
  unsigned short* wb3 = wb2 + 256 * 512;          // 16*256
  unsigned short* Qb  = wb3 + 16 * 256;           // 2*N*128
  unsigned short* Kb  = Qb + 2 * N_ * HD_;        // 2*N*128
  unsigned short* Vt  = Kb + 2 * N_ * HD_;        // 2*128*N
  unsigned short* t1b = Vt + 2 * HD_ * N_;        // E*512 (t1)
  unsigned short* t2b = t1b + (size_t)E_ * 512;   // retired eab region (reused below)
  int* cnt  = (int*)(t2b + (size_t)E_ * 256);     // 4096
  int* off  = cnt + 4096;                         // 4097
  int* cur  = off + 4100;                         // 4096
  int* perm = cur + 4096;                         // E
  unsigned short* xbp = (unsigned short*)(perm + E_);  // N*D bf16
  unsigned short* lwb = xbp + (size_t)N_ * D_;    // 256*16 bf16 lin_w (unused fast path)
  unsigned short* inb = lwb + 256 * DIN_;         // N*D bf16 input
  unsigned short* h0b = inb + (size_t)N_ * D_;    // N*D bf16 h0
  unsigned short* hgb = h0b + (size_t)N_ * D_;    // N*D bf16 h_global
  unsigned short* wqb = hgb + (size_t)N_ * D_;    // 768*256 bf16 in_proj
  unsigned short* wlT = wqb + 768 * 256;          // 256*512 bf16 Wl^T
  unsigned short* wgT = wlT + 256 * 512;          // 256*512 bf16 Wg^T
  unsigned short* opwb = wgT + 256 * 512;         // 256*256 bf16 out_proj
  unsigned short* attob = (unsigned short*)qkv;   // N*D bf16 (qkv region reused post-split)
  // Pac overlays the qkv region (12.6 MB >= 8 MB) AFTER out_proj consumed attob.
  unsigned short* Pac = (unsigned short*)qkv;     // 4096*1024 bf16 (8 MB)
  // M-fold scratch lives in the retired eab region (64 MB free).
  unsigned short* Mb_ = t2b;                      // 512*16 bf16
  float* cbv = (float*)(t2b + 8192);              // 512 f32
  const size_t fast_need = (size_t)((char*)(opwb + 256 * 256) - (char*)d_ws);
  const bool fast = ws_size >= fast_need;

  if (fast) {
    // merged preps: weights, Wl/Wg transpose, input/h0 bf16, M/cb fold
    k_prep_w<<<dim3((794624 + 255) / 256), 256, 0, stream>>>(
        w1, w2, w3, lin_w, ipw, opw, wb1, wb2, wb3, lwb, wqb, opwb);
    k_prep_t<<<dim3((262144 + 255) / 256), 256, 0, stream>>>(Wl, Wg, wlT, wgT);
    k_prep_x<<<dim3((2097152 + 255) / 256), 256, 0, stream>>>(input, h0, inb, h0b);
    k_prep_m<<<dim3(32), 256, 0, stream>>>(w1, lin_w, lin_b, b1, Mb_, cbv);

    // CSR build + lin-folded gather aggregation (eab never materialized)
    k_zero<<<dim3(16), 256, 0, stream>>>(cnt, 4096);
    k_hist<<<dim3(E_ / 256), 256, 0, stream>>>(adj, cnt);
    k_scan<<<dim3(1), 1024, 0, stream>>>(cnt, off, cur);
    k_bucket<<<dim3(E_ / 256), 256, 0, stream>>>(adj, cur, perm);
    k_gather<<<dim3(N_), 256, 0, stream>>>(input, adj, dmap, nrm, lin_w, lin_b,
                                           off, perm, xout);
    k_f2b<<<dim3(N_ * D_ / 256), 256, 0, stream>>>(xout, xbp, N_ * D_);

    // MHA: MFMA qkv -> split -> MFMA flash attn (dual out) -> MFMA out_proj
    k_qkv_mfma<<<dim3(192), 256, 0, stream>>>(inb, wqb, ipb, qkv);
    k_qk2b<<<dim3(N_ * 512 / 8 / 256), 256, 0, stream>>>(qkv, Qb, Kb);
    k_v2t<<<dim3(N_ / 64, 2), 256, 0, stream>>>(qkv, Vt);
    k_attn_mfma<<<dim3(N_ / 16, 2), 256, 0, stream>>>(Qb, Kb, Vt, atto, attob);
    k_outproj_mfma<<<dim3(64), 256, 0, stream>>>(attob, opwb, opb, hgl, hgb);

    // output[N,D] via MFMA
    k_final_mfma<<<dim3(64), 256, 0, stream>>>(xbp, h0b, hgb, wlT, wgT,
                                               xout, hgl, h0, alpha, lamda, lll, out);

    // dm_out[E,16]: node GEMM (Pac in retired qkv region) -> folded gemm1c -> gemm23
    k_node_pac<<<dim3(256), 256, 0, stream>>>(xbp, wb1, Pac);
    k_mlp_gemm1c<<<dim3(E_ / 128 * 4), 256, 0, stream>>>(dmap, adj, Pac, Mb_, cbv, t1b);
    k_mlp_gemm23<<<dim3(E_ / 128), 256, 0, stream>>>(t1b, wb2, b2, wb3, b3, dmo);
  } else {
    k_f2b<<<dim3((512 * 768 + 255) / 256), 256, 0, stream>>>(w1, wb1, 512 * 768);
    k_f2b<<<dim3((256 * 512 + 255) / 256), 256, 0, stream>>>(w2, wb2, 256 * 512);
    k_f2b<<<dim3((16 * 256 + 255) / 256), 256, 0, stream>>>(w3, wb3, 16 * 256);
    k_copy4<<<dim3(N_ * D_ / 4 / 256), 256, 0, stream>>>((const float4*)input, (float4*)xout,
                                                         N_ * D_ / 4);
    k_scatter<<<dim3(E_ / 4), 256, 0, stream>>>(input, adj, dmap, nrm, lin_w, lin_b, xout);
    k_gemm_bt<<<dim3(D3_ / 64, N_ / 64), 256, 0, stream>>>(input, ipw, ipb, qkv, N_, D3_, D_);
    k_qk2b<<<dim3(N_ * 512 / 8 / 256), 256, 0, stream>>>(qkv, Qb, Kb);
    k_v2t<<<dim3(N_ / 64, 2), 256, 0, stream>>>(qkv, Vt);
    k_attn_mfma<<<dim3(N_ / 16, 2), 256, 0, stream>>>(Qb, Kb, Vt, atto, (unsigned short*)qkv);
    k_gemm_bt<<<dim3(D_ / 64, N_ / 64), 256, 0, stream>>>(atto, opw, opb, hgl, N_, D_, D_);
    k_final<<<dim3(4, N_ / 64), 256, 0, stream>>>(xout, hgl, h0, Wl, Wg, alpha, lamda, lll, out);
    k_edge_mlp_mfma<<<dim3(E_ / 32), 256, 0, stream>>>(xout, adj, dmap, lin_w, lin_b,
                                                       wb1, b1, wb2, b2, wb3, b3, dmo);
  }
}